// Round 8
// baseline (200.904 us; speedup 1.0000x reference)
//
#include <hip/hip_runtime.h>
#include <math.h>

#ifndef M_PI
#define M_PI 3.14159265358979323846
#endif

typedef float fx4 __attribute__((ext_vector_type(4)));
typedef __bf16 bf16x8 __attribute__((ext_vector_type(8)));
typedef __bf16 bf16x4 __attribute__((ext_vector_type(4)));

__device__ __forceinline__ unsigned short f2bf(float f){
  union { float f; unsigned u; } v; v.f = f;
  unsigned r = v.u + 0x7FFFu + ((v.u >> 16) & 1u);
  return (unsigned short)(r >> 16);
}
__device__ __forceinline__ float bf2f(unsigned short u){
  union { unsigned u; float f; } v; v.u = ((unsigned)u) << 16;
  return v.f;
}
// swizzled byte offset within a [row][128] bf16 tile (256 B rows)
__device__ __forceinline__ int swz(int row, int colbyte){
  return row*256 + (colbyte ^ ((row & 7) << 4));
}

// Double-buffered 128-deep (per-wave 64x64) MFMA GEMM core (4-wave kernels).
template<typename FA, typename FB>
__device__ __forceinline__ void run_gemm(FA la, FB lb, fx4 (&acc)[4][4]){
  bf16x8 a[2][4], b[2][4];
  #pragma unroll
  for (int mi=0;mi<4;mi++){ a[0][mi]=la(mi,0); b[0][mi]=lb(mi,0); }
  #pragma unroll
  for (int ks=0; ks<4; ks++){
    int cur = ks&1, nxt = cur^1;
    if (ks<3){
      #pragma unroll
      for (int mi=0;mi<4;mi++){ a[nxt][mi]=la(mi,ks+1); b[nxt][mi]=lb(mi,ks+1); }
    }
    #pragma unroll
    for (int mi=0;mi<4;mi++)
      #pragma unroll
      for (int ni=0;ni<4;ni++)
        acc[mi][ni] = __builtin_amdgcn_mfma_f32_16x16x32_bf16(a[cur][mi], b[cur][ni], acc[mi][ni], 0, 0, 0);
  }
}

// 8-wave variant: per-wave 64x32 tile (A rows wm*64+mi*16, B rows wn*32+ni*16).
template<typename FA, typename FB>
__device__ __forceinline__ void run_gemm8(FA la, FB lb, fx4 (&acc)[4][2]){
  #pragma unroll
  for (int ks=0; ks<4; ks++){
    bf16x8 a[4], b[2];
    #pragma unroll
    for (int mi=0;mi<4;mi++) a[mi]=la(mi,ks);
    #pragma unroll
    for (int ni=0;ni<2;ni++) b[ni]=lb(ni,ks);
    #pragma unroll
    for (int mi=0;mi<4;mi++)
      #pragma unroll
      for (int ni=0;ni<2;ni++)
        acc[mi][ni] = __builtin_amdgcn_mfma_f32_16x16x32_bf16(a[mi], b[ni], acc[mi][ni], 0, 0, 0);
  }
}

// ---------------- prep: DCT basis (bf16) + weight casts ----------------
__global__ __launch_bounds__(128) void prep_kernel(
    const float* __restrict__ in_w, const float* __restrict__ ph_w,
    const float* __restrict__ out_w,
    unsigned short* __restrict__ basis_bf, unsigned short* __restrict__ basisT_bf,
    unsigned short* __restrict__ ph_w_bf, unsigned short* __restrict__ in_w_bf,
    unsigned short* __restrict__ out_w_bf)
{
  int n = blockIdx.x;     // freq
  int h = threadIdx.x;    // pos
  double arg = (double)(n*(2*h+1)) * (M_PI/256.0);
  double v = cos(arg) * 0.125;           // sqrt(2/128) = 0.125
  if (n==0) v *= 0.7071067811865476;
  unsigned short bv = f2bf((float)v);
  basis_bf[n*128+h]  = bv;
  basisT_bf[h*128+n] = bv;
  ph_w_bf[n*128+h]  = f2bf(ph_w[n*128+h]);
  in_w_bf[n*128+h]        = f2bf(in_w[n*128+h]);
  in_w_bf[(n+128)*128+h]  = f2bf(in_w[(n+128)*128+h]);
  out_w_bf[n*128+h]       = f2bf(out_w[n*128+h]);
}

// ---------------- cast freq_embed fp32 -> bf16, flat ----------------
__global__ __launch_bounds__(256) void castfe_kernel(
  const float* __restrict__ fe, unsigned short* __restrict__ feb)
{
  int idx = blockIdx.x*256 + threadIdx.x;     // 262144 threads, 8 floats each
  const float* s = fe + (size_t)idx*8;
  float4 f0 = *(const float4*)s;
  float4 f1 = *(const float4*)(s+4);
  unsigned short o[8];
  o[0]=f2bf(f0.x); o[1]=f2bf(f0.y); o[2]=f2bf(f0.z); o[3]=f2bf(f0.w);
  o[4]=f2bf(f1.x); o[5]=f2bf(f1.y); o[6]=f2bf(f1.z); o[7]=f2bf(f1.w);
  *(int4*)(feb + (size_t)idx*8) = *(const int4*)o;
}

// ---------------- projk: proj = feb[16384,128] @ ph_w^T -> projT[c][r] fp32 ----------------
__global__ __launch_bounds__(256) void projk_kernel(
  const unsigned short* __restrict__ feb, const unsigned short* __restrict__ ph_w_bf,
  float* __restrict__ projT)
{
  int r0 = blockIdx.x * 128;
  int t = threadIdx.x;
  int l = t & 63, wid = t >> 6;
  int wm = wid >> 1, wn = wid & 1;
  int lr = l & 15, lk = (l>>4)*8, ld4 = (l>>4)*4;
  fx4 acc[4][4];
  #pragma unroll
  for (int i=0;i<4;i++) for (int j=0;j<4;j++) acc[i][j] = (fx4){0.f,0.f,0.f,0.f};
  run_gemm(
    [&](int mi,int ks)->bf16x8{ return *(const bf16x8*)(feb + (size_t)(r0 + wm*64+mi*16+lr)*128 + ks*32+lk); },
    [&](int ni,int ks)->bf16x8{ return *(const bf16x8*)(ph_w_bf + (size_t)(wn*64+ni*16+lr)*128 + ks*32+lk); },
    acc);
  #pragma unroll
  for (int mi=0;mi<4;mi++)
    #pragma unroll
    for (int ni=0;ni<4;ni++){
      int c = wn*64 + ni*16 + lr;
      int r = r0 + wm*64 + mi*16 + ld4;
      *(fx4*)(projT + (size_t)c*16384 + r) = acc[mi][ni];
    }
}

// ---------------- modfin: factor -> modT[c][q][p]  (q = fe-col = freq-w, p = fe-row = freq-h)
__global__ __launch_bounds__(256) void modfin_kernel(
  const float* __restrict__ projT, const float* __restrict__ ph_b,
  const float* __restrict__ wave_speed, const float* __restrict__ damping,
  float* __restrict__ modT)
{
  int blk = blockIdx.x;
  int c = blk >> 4, qb = blk & 15;
  int t = threadIdx.x;
  int q = qb*8 + (t>>5);
  int p0 = (t & 31)*4;
  float ws0 = wave_speed[0];
  float dmp = damping[0];
  float inv = 1.0f / fmaxf(fabsf(ws0), 1e-6f);
  float dampf = 1.0f + 0.5f*dmp;
  float bc = ph_b[c];
  const float* src = projT + (size_t)c*16384 + q;
  float o[4];
  #pragma unroll
  for (int i=0;i<4;i++){
    float v = src[(size_t)(p0+i)*128] + bc;
    float g = 0.5f*v*(1.0f + erff(v*0.70710678118f));
    float wp = ws0*g;
    o[i] = __cosf(wp) + __sinf(wp)*inv*dampf;
  }
  *(float4*)(modT + ((size_t)c*128 + q)*128 + p0) = make_float4(o[0],o[1],o[2],o[3]);
}

// ---------------- depthwise 3x3 conv, NCHW fp32 -> NCHW bf16 (rolling-row, shfl halo) ----
__global__ __launch_bounds__(256) void dwconv_kernel(
  const float* __restrict__ x, const float* __restrict__ dw_w,
  const float* __restrict__ dw_b, unsigned short* __restrict__ conv)
{
  int blk = blockIdx.x;          // plane*4 + band
  int plane = blk >> 2, band = blk & 3;
  int c = plane & 127;
  const float* xp = x + (size_t)plane*16384;
  unsigned short* op = conv + (size_t)plane*16384;
  const float* kw = dw_w + c*9;
  float k0=kw[0],k1=kw[1],k2=kw[2],k3=kw[3],k4=kw[4],k5=kw[5],k6=kw[6],k7=kw[7],k8=kw[8];
  float bias = dw_b[c];
  int t = threadIdx.x;
  int q = t & 31;
  int w0 = q*4;
  int rg = t >> 5;
  int h0 = band*32 + rg*4;       // 4 output rows h0..h0+3
  bool le = (q==0), re = (q==31);

  float4 fA, fB, fC; float lA,rA,lB,rB,lC,rC;
  #define LOADROW(hh, f, l, r) { \
    int hc = (hh)<0 ? 0 : ((hh)>127 ? 127 : (hh)); \
    f = *(const float4*)(xp + hc*128 + w0); \
    float lu = __shfl_up(f.w, 1, 32); \
    float rd = __shfl_down(f.x, 1, 32); \
    l = le ? 0.f : lu; \
    r = re ? 0.f : rd; \
    if ((hh)<0 || (hh)>127){ f = make_float4(0.f,0.f,0.f,0.f); l=0.f; r=0.f; } \
  }
  LOADROW(h0-1, fA,lA,rA);
  LOADROW(h0,   fB,lB,rB);
  #pragma unroll
  for (int i=0;i<4;i++){
    LOADROW(h0+1+i, fC,lC,rC);
    float4 o;
    o.x = bias; o.y = bias; o.z = bias; o.w = bias;
    o.x = fmaf(k0,lA,  fmaf(k1,fA.x, fmaf(k2,fA.y, o.x)));
    o.y = fmaf(k0,fA.x,fmaf(k1,fA.y, fmaf(k2,fA.z, o.y)));
    o.z = fmaf(k0,fA.y,fmaf(k1,fA.z, fmaf(k2,fA.w, o.z)));
    o.w = fmaf(k0,fA.z,fmaf(k1,fA.w, fmaf(k2,rA,   o.w)));
    o.x = fmaf(k3,lB,  fmaf(k4,fB.x, fmaf(k5,fB.y, o.x)));
    o.y = fmaf(k3,fB.x,fmaf(k4,fB.y, fmaf(k5,fB.z, o.y)));
    o.z = fmaf(k3,fB.y,fmaf(k4,fB.z, fmaf(k5,fB.w, o.z)));
    o.w = fmaf(k3,fB.z,fmaf(k4,fB.w, fmaf(k5,rB,   o.w)));
    o.x = fmaf(k6,lC,  fmaf(k7,fC.x, fmaf(k8,fC.y, o.x)));
    o.y = fmaf(k6,fC.x,fmaf(k7,fC.y, fmaf(k8,fC.z, o.y)));
    o.z = fmaf(k6,fC.y,fmaf(k7,fC.z, fmaf(k8,fC.w, o.z)));
    o.w = fmaf(k6,fC.z,fmaf(k7,fC.w, fmaf(k8,rC,   o.w)));
    bf16x4 v;
    v[0]=(__bf16)o.x; v[1]=(__bf16)o.y; v[2]=(__bf16)o.z; v[3]=(__bf16)o.w;
    *(bf16x4*)(op + (size_t)(h0+i)*128 + w0) = v;
    fA=fB; lA=lB; rA=rB;
    fB=fC; lB=lC; rB=rC;
  }
  #undef LOADROW
}

// ---------------- in_proj MFMA: per (b,h): [w]x[c] @ in_w^T -> carrier NCHW bf16, silu(gate) BHWC bf16
__global__ __launch_bounds__(512) void inproj_kernel(
  const unsigned short* __restrict__ conv, const unsigned short* __restrict__ in_w_bf,
  const float* __restrict__ in_b, unsigned short* __restrict__ carrier,
  unsigned short* __restrict__ gate)
{
  __shared__ char A[32768];   // [w][c] swizzled bf16; reused as gate transpose buffer
  int blk = blockIdx.x; int b = blk>>7, h = blk&127;
  const unsigned short* C = conv + (size_t)b*2097152 + h*128;  // + c*16384 + w
  int t = threadIdx.x;
  // stage A: transpose conv [c][w] -> LDS [w][c] via 4-channel packs
  {
    int wl = t & 63, grp = t >> 6;   // grp 0..7
    #pragma unroll
    for (int p=0;p<2;p++){
      int w = wl + 64*p;
      #pragma unroll
      for (int q=0;q<4;q++){
        int c0 = (q*8 + grp)*4;
        ushort4 v;
        v.x = C[(size_t)(c0+0)*16384 + w];
        v.y = C[(size_t)(c0+1)*16384 + w];
        v.z = C[(size_t)(c0+2)*16384 + w];
        v.w = C[(size_t)(c0+3)*16384 + w];
        *(ushort4*)(A + swz(w, c0*2)) = v;
      }
    }
  }
  __syncthreads();
  int l = t & 63, wid = t >> 6;
  int wm = wid >> 2, wn = wid & 3;   // 2 x 4 waves, 64x64 quadrants over M=128,N=256
  int lr = l & 15, lk = (l>>4)*8, ld4 = (l>>4)*4;
  fx4 acc[4][4];
  #pragma unroll
  for (int i=0;i<4;i++) for (int j=0;j<4;j++) acc[i][j] = (fx4){0.f,0.f,0.f,0.f};
  run_gemm(
    [&](int mi,int ks)->bf16x8{ return *(const bf16x8*)(A + swz(wm*64+mi*16+lr, (ks*32+lk)*2)); },
    [&](int ni,int ks)->bf16x8{ return *(const bf16x8*)(in_w_bf + (size_t)(wn*64+ni*16+lr)*128 + ks*32+lk); },
    acc);
  __syncthreads();   // done reading A; gate waves will overwrite it
  if (wn < 2){
    // carrier: n in [0,128): store bf16 NCHW, 4 consecutive w per 8B store
    #pragma unroll
    for (int mi=0;mi<4;mi++)
      #pragma unroll
      for (int ni=0;ni<4;ni++){
        int n = wn*64 + ni*16 + lr;
        int w0 = wm*64 + mi*16 + ld4;
        float bias = in_b[n];
        ushort4 v;
        v.x=f2bf(acc[mi][ni][0]+bias); v.y=f2bf(acc[mi][ni][1]+bias);
        v.z=f2bf(acc[mi][ni][2]+bias); v.w=f2bf(acc[mi][ni][3]+bias);
        *(ushort4*)(carrier + (size_t)(b*128+n)*16384 + h*128 + w0) = v;
      }
  } else {
    // gate: n in [128,256): silu, write transposed [w][c] into LDS
    #pragma unroll
    for (int mi=0;mi<4;mi++)
      #pragma unroll
      for (int ni=0;ni<4;ni++){
        int n = wn*64 + ni*16 + lr;     // 128..255
        int c = n - 128;
        int w0 = wm*64 + mi*16 + ld4;
        float bias = in_b[n];
        #pragma unroll
        for (int r=0;r<4;r++){
          float v = acc[mi][ni][r] + bias;
          float s = v / (1.0f + __expf(-v));
          *(unsigned short*)(A + swz(w0+r, c*2)) = f2bf(s);
        }
      }
  }
  __syncthreads();
  // copy gate LDS [w][c] -> global BHWC bf16, coalesced
  {
    unsigned short* gout = gate + (size_t)blk*16384;   // [w][c]
    int w = t >> 2, cq = (t & 3) * 32;
    #pragma unroll
    for (int i=0;i<4;i++){
      int c0 = cq + i*8;
      int4 v = *(const int4*)(A + swz(w, c0*2));
      *(int4*)(gout + w*128 + c0) = v;
    }
  }
}

// ---------------- fused wave kernel: 4 chained MFMA GEMMs per (b,c) slice, 8 waves ----------------
__global__ __launch_bounds__(512) void wave_kernel(
  const unsigned short* __restrict__ carrier,
  const unsigned short* __restrict__ basis,    // [f][pos] bf16
  const unsigned short* __restrict__ basisT,   // [pos][f] bf16
  const float* __restrict__ modT,              // [c][w-freq][h-freq] fp32
  unsigned short* __restrict__ fused)
{
  __shared__ char U[32768];
  int blk = blockIdx.x;
  int c = blk & 127;
  const unsigned short* X = carrier + (size_t)blk*16384;  // [h][w]
  unsigned short* F = fused + (size_t)blk*16384;          // [h][w]
  int t = threadIdx.x;
  int l = t & 63, wid = t >> 6;       // 8 waves
  int wm = wid >> 2, wn = wid & 3;    // A-tile rows wm*64.., B-tile rows wn*32..
  int lr = l & 15, lk = (l>>4)*8, ld4 = (l>>4)*4;
  fx4 acc[4][2];

  // GEMM1: D1[m][h] = (X @ Bw^T)^T view   A=X rows h, B=basis rows m
  #pragma unroll
  for (int i=0;i<4;i++) for (int j=0;j<2;j++) acc[i][j] = (fx4){0.f,0.f,0.f,0.f};
  run_gemm8(
    [&](int mi,int ks)->bf16x8{ return *(const bf16x8*)(X + (size_t)(wm*64+mi*16+lr)*128 + ks*32+lk); },
    [&](int ni,int ks)->bf16x8{ return *(const bf16x8*)(basis + (size_t)(wn*32+ni*16+lr)*128 + ks*32+lk); },
    acc);
  // U1 = D1^T : [m][h]
  #pragma unroll
  for (int mi=0;mi<4;mi++)
    #pragma unroll
    for (int ni=0;ni<2;ni++){
      int m = wn*32 + ni*16 + lr, h0 = wm*64 + mi*16 + ld4;
      bf16x4 v;
      v[0]=(__bf16)acc[mi][ni][0]; v[1]=(__bf16)acc[mi][ni][1];
      v[2]=(__bf16)acc[mi][ni][2]; v[3]=(__bf16)acc[mi][ni][3];
      *(bf16x4*)(U + swz(m, h0*2)) = v;
    }
  __syncthreads();

  // GEMM2: D2[n][m]  A=basis rows n, B=U1 rows m; then modulate
  #pragma unroll
  for (int i=0;i<4;i++) for (int j=0;j<2;j++) acc[i][j] = (fx4){0.f,0.f,0.f,0.f};
  run_gemm8(
    [&](int mi,int ks)->bf16x8{ return *(const bf16x8*)(basis + (size_t)(wm*64+mi*16+lr)*128 + ks*32+lk); },
    [&](int ni,int ks)->bf16x8{ return *(const bf16x8*)(U + swz(wn*32+ni*16+lr, (ks*32+lk)*2)); },
    acc);
  {
    const float* Mc = modT + (size_t)c*16384;
    #pragma unroll
    for (int mi=0;mi<4;mi++)
      #pragma unroll
      for (int ni=0;ni<2;ni++){
        int n0 = wm*64 + mi*16 + ld4, m = wn*32 + ni*16 + lr;
        fx4 mv = *(const fx4*)(Mc + (size_t)m*128 + n0);
        acc[mi][ni] *= mv;
      }
  }
  __syncthreads();   // all reads of U1 done
  // U2 = D2^T : [m][n]
  #pragma unroll
  for (int mi=0;mi<4;mi++)
    #pragma unroll
    for (int ni=0;ni<2;ni++){
      int m = wn*32 + ni*16 + lr, n0 = wm*64 + mi*16 + ld4;
      bf16x4 v;
      v[0]=(__bf16)acc[mi][ni][0]; v[1]=(__bf16)acc[mi][ni][1];
      v[2]=(__bf16)acc[mi][ni][2]; v[3]=(__bf16)acc[mi][ni][3];
      *(bf16x4*)(U + swz(m, n0*2)) = v;
    }
  __syncthreads();

  // GEMM3: D3[h][m]  A=U2 rows m (k=n), B=basisT rows h (k=n)
  #pragma unroll
  for (int i=0;i<4;i++) for (int j=0;j<2;j++) acc[i][j] = (fx4){0.f,0.f,0.f,0.f};
  run_gemm8(
    [&](int mi,int ks)->bf16x8{ return *(const bf16x8*)(U + swz(wm*64+mi*16+lr, (ks*32+lk)*2)); },
    [&](int ni,int ks)->bf16x8{ return *(const bf16x8*)(basisT + (size_t)(wn*32+ni*16+lr)*128 + ks*32+lk); },
    acc);
  __syncthreads();   // all reads of U2 done
  // U3 = D3^T : [h][m]
  #pragma unroll
  for (int mi=0;mi<4;mi++)
    #pragma unroll
    for (int ni=0;ni<2;ni++){
      int hh = wn*32 + ni*16 + lr, m0 = wm*64 + mi*16 + ld4;
      bf16x4 v;
      v[0]=(__bf16)acc[mi][ni][0]; v[1]=(__bf16)acc[mi][ni][1];
      v[2]=(__bf16)acc[mi][ni][2]; v[3]=(__bf16)acc[mi][ni][3];
      *(bf16x4*)(U + swz(hh, m0*2)) = v;
    }
  __syncthreads();

  // GEMM4: D4[h][w]  A=basisT rows w (k=m), B=U3 rows h (k=m)
  #pragma unroll
  for (int i=0;i<4;i++) for (int j=0;j<2;j++) acc[i][j] = (fx4){0.f,0.f,0.f,0.f};
  run_gemm8(
    [&](int mi,int ks)->bf16x8{ return *(const bf16x8*)(basisT + (size_t)(wm*64+mi*16+lr)*128 + ks*32+lk); },
    [&](int ni,int ks)->bf16x8{ return *(const bf16x8*)(U + swz(wn*32+ni*16+lr, (ks*32+lk)*2)); },
    acc);
  // store fused[h][w] bf16
  #pragma unroll
  for (int mi=0;mi<4;mi++)
    #pragma unroll
    for (int ni=0;ni<2;ni++){
      int hh = wn*32 + ni*16 + lr, w0 = wm*64 + mi*16 + ld4;
      bf16x4 v;
      v[0]=(__bf16)acc[mi][ni][0]; v[1]=(__bf16)acc[mi][ni][1];
      v[2]=(__bf16)acc[mi][ni][2]; v[3]=(__bf16)acc[mi][ni][3];
      *(bf16x4*)(F + hh*128 + w0) = v;
    }
}

// ---------------- final: LN * silu(gate) @ out_w^T + b -> out NCHW fp32 ----------------
__global__ __launch_bounds__(256) void final_kernel(
  const unsigned short* __restrict__ fused, const unsigned short* __restrict__ gate,
  const unsigned short* __restrict__ out_w_bf, const float* __restrict__ out_b,
  const float* __restrict__ ln_w, const float* __restrict__ ln_b,
  float* __restrict__ out)
{
  __shared__ char Fl[32768];   // F [c][w] swizzled bf16
  __shared__ char Al[32768];   // act [w][c] swizzled bf16
  __shared__ float red[256], red2[256];
  __shared__ float mu[128], rs[128];
  int blk = blockIdx.x; int b = blk>>7, h = blk&127;
  const unsigned short* Fsrc = fused + (size_t)b*2097152 + h*128;  // + c*16384 + w
  const unsigned short* G = gate + (size_t)blk*16384;              // [w][c]
  int t = threadIdx.x;
  // stage F [c][w]
  {
    int c = t>>1, wq = (t&1)*64;
    #pragma unroll
    for (int i=0;i<8;i++){
      int w0 = wq + i*8;
      int4 v = *(const int4*)(Fsrc + (size_t)c*16384 + w0);
      *(int4*)(Fl + swz(c, w0*2)) = v;
    }
  }
  __syncthreads();
  // LN stats per w (reduce over c)
  {
    int w = t&127, half = t>>7;
    float s=0.f, q=0.f;
    for (int i=0;i<64;i++){
      int c = half*64 + i;
      float f = bf2f(*(const unsigned short*)(Fl + swz(c, w*2)));
      s += f; q = fmaf(f,f,q);
    }
    red[t]=s; red2[t]=q;
  }
  __syncthreads();
  if (t < 128){
    float ss = red[t]+red[t+128], qq = red2[t]+red2[t+128];
    float m = ss*(1.f/128.f);
    float var = qq*(1.f/128.f) - m*m;
    mu[t]=m; rs[t]=rsqrtf(var+1e-5f);
  }
  __syncthreads();
  // act[w][c] = LN(F)*silu_gate
  {
    int w = t>>1, cq = (t&1)*64;
    float m_ = mu[w], r_ = rs[w];
    #pragma unroll
    for (int i=0;i<8;i++){
      int c0 = cq + i*8;
      ushort4 g0 = *(const ushort4*)(G + (size_t)w*128 + c0);
      ushort4 g1 = *(const ushort4*)(G + (size_t)w*128 + c0 + 4);
      unsigned short ov[8];
      unsigned short gv[8] = {g0.x,g0.y,g0.z,g0.w,g1.x,g1.y,g1.z,g1.w};
      #pragma unroll
      for (int j=0;j<8;j++){
        int cc = c0+j;
        float f = bf2f(*(const unsigned short*)(Fl + swz(cc, w*2)));
        float a = fmaf((f-m_)*r_, ln_w[cc], ln_b[cc]) * bf2f(gv[j]);
        ov[j] = f2bf(a);
      }
      *(int4*)(Al + swz(w, c0*2)) = *(const int4*)ov;
    }
  }
  __syncthreads();
  // MFMA: D[w][j] = act @ out_w^T
  int l = t & 63, wid = t >> 6;
  int wm = wid >> 1, wn = wid & 1;
  int lr = l & 15, lk = (l>>4)*8, ld4 = (l>>4)*4;
  fx4 acc[4][4];
  #pragma unroll
  for (int i=0;i<4;i++) for (int j=0;j<4;j++) acc[i][j] = (fx4){0.f,0.f,0.f,0.f};
  run_gemm(
    [&](int mi,int ks)->bf16x8{ return *(const bf16x8*)(Al + swz(wm*64+mi*16+lr, (ks*32+lk)*2)); },
    [&](int ni,int ks)->bf16x8{ return *(const bf16x8*)(out_w_bf + (size_t)(wn*64+ni*16+lr)*128 + ks*32+lk); },
    acc);
  #pragma unroll
  for (int mi=0;mi<4;mi++)
    #pragma unroll
    for (int ni=0;ni<4;ni++){
      int j = wn*64 + ni*16 + lr, w0 = wm*64 + mi*16 + ld4;
      float bj = out_b[j];
      fx4 o = acc[mi][ni];
      o[0]+=bj; o[1]+=bj; o[2]+=bj; o[3]+=bj;
      *(fx4*)(out + ((size_t)(b*128 + j)*128 + h)*128 + w0) = o;
    }
}

extern "C" void kernel_launch(void* const* d_in, const int* in_sizes, int n_in,
                              void* d_out, int out_size, void* d_ws, size_t ws_size,
                              hipStream_t stream)
{
  const float* x      = (const float*)d_in[0];
  const float* dw_w   = (const float*)d_in[1];
  const float* dw_b   = (const float*)d_in[2];
  const float* in_w   = (const float*)d_in[3];
  const float* in_b   = (const float*)d_in[4];
  const float* out_w  = (const float*)d_in[5];
  const float* out_b  = (const float*)d_in[6];
  const float* ln_w   = (const float*)d_in[7];
  const float* ln_b   = (const float*)d_in[8];
  const float* ph_w   = (const float*)d_in[9];
  const float* ph_b   = (const float*)d_in[10];
  const float* wsp    = (const float*)d_in[11];
  const float* dmp    = (const float*)d_in[12];
  const float* fe     = (const float*)d_in[13];
  float* outp = (float*)d_out;

  float* modT  = (float*)d_ws;                 // 2,097,152 f32, [c][w-freq][h-freq]
  float* projT = modT + 2097152;               // 2,097,152 f32
  unsigned short* feb      = (unsigned short*)(projT + 2097152);  // 2,097,152 bf16
  unsigned short* conv     = feb     + 2097152;
  unsigned short* carrier  = conv    + 16777216;
  unsigned short* gate     = carrier + 16777216;
  unsigned short* fusedb   = gate    + 16777216;
  unsigned short* basis_bf = fusedb  + 16777216;
  unsigned short* basisT_bf= basis_bf + 16384;
  unsigned short* in_w_bf  = basisT_bf + 16384;
  unsigned short* out_w_bf = in_w_bf + 32768;
  unsigned short* ph_w_bf  = out_w_bf + 16384;

  prep_kernel<<<128,128,0,stream>>>(in_w, ph_w, out_w, basis_bf, basisT_bf, ph_w_bf, in_w_bf, out_w_bf);
  castfe_kernel<<<1024,256,0,stream>>>(fe, feb);
  projk_kernel<<<128,256,0,stream>>>(feb, ph_w_bf, projT);
  modfin_kernel<<<2048,256,0,stream>>>(projT, ph_b, wsp, dmp, modT);
  dwconv_kernel<<<4096,256,0,stream>>>(x, dw_w, dw_b, conv);
  inproj_kernel<<<1024,512,0,stream>>>(conv, in_w_bf, in_b, carrier, gate);
  wave_kernel<<<1024,512,0,stream>>>(carrier, basis_bf, basisT_bf, modT, fusedb);
  final_kernel<<<1024,256,0,stream>>>(fusedb, gate, out_w_bf, out_b, ln_w, ln_b, outp);
}

// Round 9
// 181.508 us; speedup vs baseline: 1.1069x; 1.1069x over previous
//
#include <hip/hip_runtime.h>
#include <math.h>

#ifndef M_PI
#define M_PI 3.14159265358979323846
#endif

typedef float fx4 __attribute__((ext_vector_type(4)));
typedef __bf16 bf16x8 __attribute__((ext_vector_type(8)));
typedef __bf16 bf16x4 __attribute__((ext_vector_type(4)));

__device__ __forceinline__ unsigned short f2bf(float f){
  union { float f; unsigned u; } v; v.f = f;
  unsigned r = v.u + 0x7FFFu + ((v.u >> 16) & 1u);
  return (unsigned short)(r >> 16);
}
__device__ __forceinline__ float bf2f(unsigned short u){
  union { unsigned u; float f; } v; v.u = ((unsigned)u) << 16;
  return v.f;
}
// swizzled byte offset within a [row][128] bf16 tile (256 B rows)
__device__ __forceinline__ int swz(int row, int colbyte){
  return row*256 + (colbyte ^ ((row & 7) << 4));
}

// Double-buffered 128-deep (per-wave 64x64) MFMA GEMM core.
template<typename FA, typename FB>
__device__ __forceinline__ void run_gemm(FA la, FB lb, fx4 (&acc)[4][4]){
  bf16x8 a[2][4], b[2][4];
  #pragma unroll
  for (int mi=0;mi<4;mi++){ a[0][mi]=la(mi,0); b[0][mi]=lb(mi,0); }
  #pragma unroll
  for (int ks=0; ks<4; ks++){
    int cur = ks&1, nxt = cur^1;
    if (ks<3){
      #pragma unroll
      for (int mi=0;mi<4;mi++){ a[nxt][mi]=la(mi,ks+1); b[nxt][mi]=lb(mi,ks+1); }
    }
    #pragma unroll
    for (int mi=0;mi<4;mi++)
      #pragma unroll
      for (int ni=0;ni<4;ni++)
        acc[mi][ni] = __builtin_amdgcn_mfma_f32_16x16x32_bf16(a[cur][mi], b[cur][ni], acc[mi][ni], 0, 0, 0);
  }
}

// ---------------- prep: DCT basis (bf16) + weight casts ----------------
__global__ __launch_bounds__(128) void prep_kernel(
    const float* __restrict__ in_w, const float* __restrict__ ph_w,
    const float* __restrict__ out_w,
    unsigned short* __restrict__ basis_bf, unsigned short* __restrict__ basisT_bf,
    unsigned short* __restrict__ ph_w_bf, unsigned short* __restrict__ in_w_bf,
    unsigned short* __restrict__ out_w_bf)
{
  int n = blockIdx.x;     // freq
  int h = threadIdx.x;    // pos
  double arg = (double)(n*(2*h+1)) * (M_PI/256.0);
  double v = cos(arg) * 0.125;           // sqrt(2/128) = 0.125
  if (n==0) v *= 0.7071067811865476;
  unsigned short bv = f2bf((float)v);
  basis_bf[n*128+h]  = bv;
  basisT_bf[h*128+n] = bv;
  ph_w_bf[n*128+h]  = f2bf(ph_w[n*128+h]);
  in_w_bf[n*128+h]        = f2bf(in_w[n*128+h]);
  in_w_bf[(n+128)*128+h]  = f2bf(in_w[(n+128)*128+h]);
  out_w_bf[n*128+h]       = f2bf(out_w[n*128+h]);
}

// ---------------- cast freq_embed fp32 -> bf16, flat ----------------
__global__ __launch_bounds__(256) void castfe_kernel(
  const float* __restrict__ fe, unsigned short* __restrict__ feb)
{
  int idx = blockIdx.x*256 + threadIdx.x;     // 262144 threads, 8 floats each
  const float* s = fe + (size_t)idx*8;
  float4 f0 = *(const float4*)s;
  float4 f1 = *(const float4*)(s+4);
  unsigned short o[8];
  o[0]=f2bf(f0.x); o[1]=f2bf(f0.y); o[2]=f2bf(f0.z); o[3]=f2bf(f0.w);
  o[4]=f2bf(f1.x); o[5]=f2bf(f1.y); o[6]=f2bf(f1.z); o[7]=f2bf(f1.w);
  *(int4*)(feb + (size_t)idx*8) = *(const int4*)o;
}

// ---------------- projk: proj = feb[16384,128] @ ph_w^T -> projT[c][r] fp32 ----------------
__global__ __launch_bounds__(256) void projk_kernel(
  const unsigned short* __restrict__ feb, const unsigned short* __restrict__ ph_w_bf,
  float* __restrict__ projT)
{
  int r0 = blockIdx.x * 128;
  int t = threadIdx.x;
  int l = t & 63, wid = t >> 6;
  int wm = wid >> 1, wn = wid & 1;
  int lr = l & 15, lk = (l>>4)*8, ld4 = (l>>4)*4;
  fx4 acc[4][4];
  #pragma unroll
  for (int i=0;i<4;i++) for (int j=0;j<4;j++) acc[i][j] = (fx4){0.f,0.f,0.f,0.f};
  run_gemm(
    [&](int mi,int ks)->bf16x8{ return *(const bf16x8*)(feb + (size_t)(r0 + wm*64+mi*16+lr)*128 + ks*32+lk); },
    [&](int ni,int ks)->bf16x8{ return *(const bf16x8*)(ph_w_bf + (size_t)(wn*64+ni*16+lr)*128 + ks*32+lk); },
    acc);
  #pragma unroll
  for (int mi=0;mi<4;mi++)
    #pragma unroll
    for (int ni=0;ni<4;ni++){
      int c = wn*64 + ni*16 + lr;
      int r = r0 + wm*64 + mi*16 + ld4;
      *(fx4*)(projT + (size_t)c*16384 + r) = acc[mi][ni];
    }
}

// ---------------- modfin: factor -> modT[c][q][p]  (q = fe-col = freq-w, p = fe-row = freq-h)
__global__ __launch_bounds__(256) void modfin_kernel(
  const float* __restrict__ projT, const float* __restrict__ ph_b,
  const float* __restrict__ wave_speed, const float* __restrict__ damping,
  float* __restrict__ modT)
{
  int blk = blockIdx.x;
  int c = blk >> 4, qb = blk & 15;
  int t = threadIdx.x;
  int q = qb*8 + (t>>5);
  int p0 = (t & 31)*4;
  float ws0 = wave_speed[0];
  float dmp = damping[0];
  float inv = 1.0f / fmaxf(fabsf(ws0), 1e-6f);
  float dampf = 1.0f + 0.5f*dmp;
  float bc = ph_b[c];
  const float* src = projT + (size_t)c*16384 + q;
  float o[4];
  #pragma unroll
  for (int i=0;i<4;i++){
    float v = src[(size_t)(p0+i)*128] + bc;
    float g = 0.5f*v*(1.0f + erff(v*0.70710678118f));
    float wp = ws0*g;
    o[i] = __cosf(wp) + __sinf(wp)*inv*dampf;
  }
  *(float4*)(modT + ((size_t)c*128 + q)*128 + p0) = make_float4(o[0],o[1],o[2],o[3]);
}

// ---------------- depthwise 3x3 conv, NCHW fp32 -> NCHW bf16 (rolling-row, shfl halo) ----
__global__ __launch_bounds__(256) void dwconv_kernel(
  const float* __restrict__ x, const float* __restrict__ dw_w,
  const float* __restrict__ dw_b, unsigned short* __restrict__ conv)
{
  int blk = blockIdx.x;          // plane*4 + band
  int plane = blk >> 2, band = blk & 3;
  int c = plane & 127;
  const float* xp = x + (size_t)plane*16384;
  unsigned short* op = conv + (size_t)plane*16384;
  const float* kw = dw_w + c*9;
  float k0=kw[0],k1=kw[1],k2=kw[2],k3=kw[3],k4=kw[4],k5=kw[5],k6=kw[6],k7=kw[7],k8=kw[8];
  float bias = dw_b[c];
  int t = threadIdx.x;
  int q = t & 31;
  int w0 = q*4;
  int rg = t >> 5;
  int h0 = band*32 + rg*4;       // 4 output rows h0..h0+3
  bool le = (q==0), re = (q==31);

  float4 fA, fB, fC; float lA,rA,lB,rB,lC,rC;
  #define LOADROW(hh, f, l, r) { \
    int hc = (hh)<0 ? 0 : ((hh)>127 ? 127 : (hh)); \
    f = *(const float4*)(xp + hc*128 + w0); \
    float lu = __shfl_up(f.w, 1, 32); \
    float rd = __shfl_down(f.x, 1, 32); \
    l = le ? 0.f : lu; \
    r = re ? 0.f : rd; \
    if ((hh)<0 || (hh)>127){ f = make_float4(0.f,0.f,0.f,0.f); l=0.f; r=0.f; } \
  }
  LOADROW(h0-1, fA,lA,rA);
  LOADROW(h0,   fB,lB,rB);
  #pragma unroll
  for (int i=0;i<4;i++){
    LOADROW(h0+1+i, fC,lC,rC);
    float4 o;
    o.x = bias; o.y = bias; o.z = bias; o.w = bias;
    o.x = fmaf(k0,lA,  fmaf(k1,fA.x, fmaf(k2,fA.y, o.x)));
    o.y = fmaf(k0,fA.x,fmaf(k1,fA.y, fmaf(k2,fA.z, o.y)));
    o.z = fmaf(k0,fA.y,fmaf(k1,fA.z, fmaf(k2,fA.w, o.z)));
    o.w = fmaf(k0,fA.z,fmaf(k1,fA.w, fmaf(k2,rA,   o.w)));
    o.x = fmaf(k3,lB,  fmaf(k4,fB.x, fmaf(k5,fB.y, o.x)));
    o.y = fmaf(k3,fB.x,fmaf(k4,fB.y, fmaf(k5,fB.z, o.y)));
    o.z = fmaf(k3,fB.y,fmaf(k4,fB.z, fmaf(k5,fB.w, o.z)));
    o.w = fmaf(k3,fB.z,fmaf(k4,fB.w, fmaf(k5,rB,   o.w)));
    o.x = fmaf(k6,lC,  fmaf(k7,fC.x, fmaf(k8,fC.y, o.x)));
    o.y = fmaf(k6,fC.x,fmaf(k7,fC.y, fmaf(k8,fC.z, o.y)));
    o.z = fmaf(k6,fC.y,fmaf(k7,fC.z, fmaf(k8,fC.w, o.z)));
    o.w = fmaf(k6,fC.z,fmaf(k7,fC.w, fmaf(k8,rC,   o.w)));
    bf16x4 v;
    v[0]=(__bf16)o.x; v[1]=(__bf16)o.y; v[2]=(__bf16)o.z; v[3]=(__bf16)o.w;
    *(bf16x4*)(op + (size_t)(h0+i)*128 + w0) = v;
    fA=fB; lA=lB; rA=rB;
    fB=fC; lB=lC; rB=rC;
  }
  #undef LOADROW
}

// ---------------- in_proj MFMA: per (b,h): [w]x[c] @ in_w^T -> carrier NCHW bf16, silu(gate) BHWC bf16
__global__ __launch_bounds__(512) void inproj_kernel(
  const unsigned short* __restrict__ conv, const unsigned short* __restrict__ in_w_bf,
  const float* __restrict__ in_b, unsigned short* __restrict__ carrier,
  unsigned short* __restrict__ gate)
{
  __shared__ char A[32768];   // [w][c] swizzled bf16; reused as gate transpose buffer
  int blk = blockIdx.x; int b = blk>>7, h = blk&127;
  const unsigned short* C = conv + (size_t)b*2097152 + h*128;  // + c*16384 + w
  int t = threadIdx.x;
  // stage A: transpose conv [c][w] -> LDS [w][c] via 4-channel packs
  {
    int wl = t & 63, grp = t >> 6;   // grp 0..7
    #pragma unroll
    for (int p=0;p<2;p++){
      int w = wl + 64*p;
      #pragma unroll
      for (int q=0;q<4;q++){
        int c0 = (q*8 + grp)*4;
        ushort4 v;
        v.x = C[(size_t)(c0+0)*16384 + w];
        v.y = C[(size_t)(c0+1)*16384 + w];
        v.z = C[(size_t)(c0+2)*16384 + w];
        v.w = C[(size_t)(c0+3)*16384 + w];
        *(ushort4*)(A + swz(w, c0*2)) = v;
      }
    }
  }
  __syncthreads();
  int l = t & 63, wid = t >> 6;
  int wm = wid >> 2, wn = wid & 3;   // 2 x 4 waves, 64x64 quadrants over M=128,N=256
  int lr = l & 15, lk = (l>>4)*8, ld4 = (l>>4)*4;
  fx4 acc[4][4];
  #pragma unroll
  for (int i=0;i<4;i++) for (int j=0;j<4;j++) acc[i][j] = (fx4){0.f,0.f,0.f,0.f};
  run_gemm(
    [&](int mi,int ks)->bf16x8{ return *(const bf16x8*)(A + swz(wm*64+mi*16+lr, (ks*32+lk)*2)); },
    [&](int ni,int ks)->bf16x8{ return *(const bf16x8*)(in_w_bf + (size_t)(wn*64+ni*16+lr)*128 + ks*32+lk); },
    acc);
  __syncthreads();   // done reading A; gate waves will overwrite it
  if (wn < 2){
    // carrier: n in [0,128): store bf16 NCHW, 4 consecutive w per 8B store
    #pragma unroll
    for (int mi=0;mi<4;mi++)
      #pragma unroll
      for (int ni=0;ni<4;ni++){
        int n = wn*64 + ni*16 + lr;
        int w0 = wm*64 + mi*16 + ld4;
        float bias = in_b[n];
        ushort4 v;
        v.x=f2bf(acc[mi][ni][0]+bias); v.y=f2bf(acc[mi][ni][1]+bias);
        v.z=f2bf(acc[mi][ni][2]+bias); v.w=f2bf(acc[mi][ni][3]+bias);
        *(ushort4*)(carrier + (size_t)(b*128+n)*16384 + h*128 + w0) = v;
      }
  } else {
    // gate: n in [128,256): silu, write transposed [w][c] into LDS
    #pragma unroll
    for (int mi=0;mi<4;mi++)
      #pragma unroll
      for (int ni=0;ni<4;ni++){
        int n = wn*64 + ni*16 + lr;     // 128..255
        int c = n - 128;
        int w0 = wm*64 + mi*16 + ld4;
        float bias = in_b[n];
        #pragma unroll
        for (int r=0;r<4;r++){
          float v = acc[mi][ni][r] + bias;
          float s = v / (1.0f + __expf(-v));
          *(unsigned short*)(A + swz(w0+r, c*2)) = f2bf(s);
        }
      }
  }
  __syncthreads();
  // copy gate LDS [w][c] -> global BHWC bf16, coalesced
  {
    unsigned short* gout = gate + (size_t)blk*16384;   // [w][c]
    int w = t >> 2, cq = (t & 3) * 32;
    #pragma unroll
    for (int i=0;i<4;i++){
      int c0 = cq + i*8;
      int4 v = *(const int4*)(A + swz(w, c0*2));
      *(int4*)(gout + w*128 + c0) = v;
    }
  }
}

// ---------------- fused wave kernel: 4 chained MFMA GEMMs, dual LDS buffers, 3 barriers ----
__global__ __launch_bounds__(256) void wave_kernel(
  const unsigned short* __restrict__ carrier,
  const unsigned short* __restrict__ basis,    // [f][pos] bf16
  const unsigned short* __restrict__ basisT,   // [pos][f] bf16
  const float* __restrict__ modT,              // [c][w-freq][h-freq] fp32
  unsigned short* __restrict__ fused)
{
  __shared__ char U[65536];
  char* bufA = U;
  char* bufB = U + 32768;
  int blk = blockIdx.x;
  int c = blk & 127;
  const unsigned short* X = carrier + (size_t)blk*16384;  // [h][w]
  unsigned short* F = fused + (size_t)blk*16384;          // [h][w]
  int t = threadIdx.x;
  int l = t & 63, wid = t >> 6;
  int wm = wid >> 1, wn = wid & 1;
  int lr = l & 15, lk = (l>>4)*8, ld4 = (l>>4)*4;
  fx4 acc[4][4];

  // GEMM1: D1[h][m] = X @ Bw^T  (A=X global rows h, B=basis global rows m, k=w)
  #pragma unroll
  for (int i=0;i<4;i++) for (int j=0;j<4;j++) acc[i][j] = (fx4){0.f,0.f,0.f,0.f};
  run_gemm(
    [&](int mi,int ks)->bf16x8{ return *(const bf16x8*)(X + (size_t)(wm*64+mi*16+lr)*128 + ks*32+lk); },
    [&](int ni,int ks)->bf16x8{ return *(const bf16x8*)(basis + (size_t)(wn*64+ni*16+lr)*128 + ks*32+lk); },
    acc);
  // U1 = D1^T : [m][h] -> bufA
  #pragma unroll
  for (int mi=0;mi<4;mi++)
    #pragma unroll
    for (int ni=0;ni<4;ni++){
      int m = wn*64 + ni*16 + lr, h0 = wm*64 + mi*16 + ld4;
      bf16x4 v;
      v[0]=(__bf16)acc[mi][ni][0]; v[1]=(__bf16)acc[mi][ni][1];
      v[2]=(__bf16)acc[mi][ni][2]; v[3]=(__bf16)acc[mi][ni][3];
      *(bf16x4*)(bufA + swz(m, h0*2)) = v;
    }
  __syncthreads();                                   // bar 1: bufA ready

  // GEMM2: D2[n][m] = Bh @ U1^T  (A=basis rows n, B=bufA rows m, k=h), then modulate
  #pragma unroll
  for (int i=0;i<4;i++) for (int j=0;j<4;j++) acc[i][j] = (fx4){0.f,0.f,0.f,0.f};
  run_gemm(
    [&](int mi,int ks)->bf16x8{ return *(const bf16x8*)(basis + (size_t)(wm*64+mi*16+lr)*128 + ks*32+lk); },
    [&](int ni,int ks)->bf16x8{ return *(const bf16x8*)(bufA + swz(wn*64+ni*16+lr, (ks*32+lk)*2)); },
    acc);
  {
    const float* Mc = modT + (size_t)c*16384;
    #pragma unroll
    for (int mi=0;mi<4;mi++)
      #pragma unroll
      for (int ni=0;ni<4;ni++){
        int n0 = wm*64 + mi*16 + ld4, m = wn*64 + ni*16 + lr;
        fx4 mv = *(const fx4*)(Mc + (size_t)m*128 + n0);
        acc[mi][ni] *= mv;
      }
  }
  // U2 = D2^T : [m][n] -> bufB  (bufA reads complete per-wave via data dependency)
  #pragma unroll
  for (int mi=0;mi<4;mi++)
    #pragma unroll
    for (int ni=0;ni<4;ni++){
      int m = wn*64 + ni*16 + lr, n0 = wm*64 + mi*16 + ld4;
      bf16x4 v;
      v[0]=(__bf16)acc[mi][ni][0]; v[1]=(__bf16)acc[mi][ni][1];
      v[2]=(__bf16)acc[mi][ni][2]; v[3]=(__bf16)acc[mi][ni][3];
      *(bf16x4*)(bufB + swz(m, n0*2)) = v;
    }
  __syncthreads();                                   // bar 2: bufB ready, bufA free

  // GEMM3: D3[m][h] = U2 @ Bh  (A=bufB rows m, B=basisT rows h, k=n)
  #pragma unroll
  for (int i=0;i<4;i++) for (int j=0;j<4;j++) acc[i][j] = (fx4){0.f,0.f,0.f,0.f};
  run_gemm(
    [&](int mi,int ks)->bf16x8{ return *(const bf16x8*)(bufB + swz(wm*64+mi*16+lr, (ks*32+lk)*2)); },
    [&](int ni,int ks)->bf16x8{ return *(const bf16x8*)(basisT + (size_t)(wn*64+ni*16+lr)*128 + ks*32+lk); },
    acc);
  // U3 = D3^T : [h][m] -> bufA
  #pragma unroll
  for (int mi=0;mi<4;mi++)
    #pragma unroll
    for (int ni=0;ni<4;ni++){
      int hh = wn*64 + ni*16 + lr, m0 = wm*64 + mi*16 + ld4;
      bf16x4 v;
      v[0]=(__bf16)acc[mi][ni][0]; v[1]=(__bf16)acc[mi][ni][1];
      v[2]=(__bf16)acc[mi][ni][2]; v[3]=(__bf16)acc[mi][ni][3];
      *(bf16x4*)(bufA + swz(hh, m0*2)) = v;
    }
  __syncthreads();                                   // bar 3: bufA(U3) ready

  // GEMM4: D4[w][h] = BwT @ U3^T  (A=basisT rows w, B=bufA rows h, k=m)
  #pragma unroll
  for (int i=0;i<4;i++) for (int j=0;j<4;j++) acc[i][j] = (fx4){0.f,0.f,0.f,0.f};
  run_gemm(
    [&](int mi,int ks)->bf16x8{ return *(const bf16x8*)(basisT + (size_t)(wm*64+mi*16+lr)*128 + ks*32+lk); },
    [&](int ni,int ks)->bf16x8{ return *(const bf16x8*)(bufA + swz(wn*64+ni*16+lr, (ks*32+lk)*2)); },
    acc);
  // store fused[h][w] bf16: D4[row=w][col=h]
  #pragma unroll
  for (int mi=0;mi<4;mi++)
    #pragma unroll
    for (int ni=0;ni<4;ni++){
      int hh = wn*64 + ni*16 + lr, w0 = wm*64 + mi*16 + ld4;
      bf16x4 v;
      v[0]=(__bf16)acc[mi][ni][0]; v[1]=(__bf16)acc[mi][ni][1];
      v[2]=(__bf16)acc[mi][ni][2]; v[3]=(__bf16)acc[mi][ni][3];
      *(bf16x4*)(F + hh*128 + w0) = v;
    }
}

// ---------------- final: LN * silu(gate) @ out_w^T + b -> out NCHW fp32 ----------------
__global__ __launch_bounds__(256) void final_kernel(
  const unsigned short* __restrict__ fused, const unsigned short* __restrict__ gate,
  const unsigned short* __restrict__ out_w_bf, const float* __restrict__ out_b,
  const float* __restrict__ ln_w, const float* __restrict__ ln_b,
  float* __restrict__ out)
{
  __shared__ char Fl[32768];   // F [c][w] swizzled bf16
  __shared__ char Al[32768];   // act [w][c] swizzled bf16
  __shared__ float red[256], red2[256];
  __shared__ float mu[128], rs[128];
  int blk = blockIdx.x; int b = blk>>7, h = blk&127;
  const unsigned short* Fsrc = fused + (size_t)b*2097152 + h*128;  // + c*16384 + w
  const unsigned short* G = gate + (size_t)blk*16384;              // [w][c]
  int t = threadIdx.x;
  // stage F [c][w]
  {
    int c = t>>1, wq = (t&1)*64;
    #pragma unroll
    for (int i=0;i<8;i++){
      int w0 = wq + i*8;
      int4 v = *(const int4*)(Fsrc + (size_t)c*16384 + w0);
      *(int4*)(Fl + swz(c, w0*2)) = v;
    }
  }
  __syncthreads();
  // LN stats per w (reduce over c)
  {
    int w = t&127, half = t>>7;
    float s=0.f, q=0.f;
    for (int i=0;i<64;i++){
      int c = half*64 + i;
      float f = bf2f(*(const unsigned short*)(Fl + swz(c, w*2)));
      s += f; q = fmaf(f,f,q);
    }
    red[t]=s; red2[t]=q;
  }
  __syncthreads();
  if (t < 128){
    float ss = red[t]+red[t+128], qq = red2[t]+red2[t+128];
    float m = ss*(1.f/128.f);
    float var = qq*(1.f/128.f) - m*m;
    mu[t]=m; rs[t]=rsqrtf(var+1e-5f);
  }
  __syncthreads();
  // act[w][c] = LN(F)*silu_gate
  {
    int w = t>>1, cq = (t&1)*64;
    float m_ = mu[w], r_ = rs[w];
    #pragma unroll
    for (int i=0;i<8;i++){
      int c0 = cq + i*8;
      ushort4 g0 = *(const ushort4*)(G + (size_t)w*128 + c0);
      ushort4 g1 = *(const ushort4*)(G + (size_t)w*128 + c0 + 4);
      unsigned short ov[8];
      unsigned short gv[8] = {g0.x,g0.y,g0.z,g0.w,g1.x,g1.y,g1.z,g1.w};
      #pragma unroll
      for (int j=0;j<8;j++){
        int cc = c0+j;
        float f = bf2f(*(const unsigned short*)(Fl + swz(cc, w*2)));
        float a = fmaf((f-m_)*r_, ln_w[cc], ln_b[cc]) * bf2f(gv[j]);
        ov[j] = f2bf(a);
      }
      *(int4*)(Al + swz(w, c0*2)) = *(const int4*)ov;
    }
  }
  __syncthreads();
  // MFMA: D[w][j] = act @ out_w^T
  int l = t & 63, wid = t >> 6;
  int wm = wid >> 1, wn = wid & 1;
  int lr = l & 15, lk = (l>>4)*8, ld4 = (l>>4)*4;
  fx4 acc[4][4];
  #pragma unroll
  for (int i=0;i<4;i++) for (int j=0;j<4;j++) acc[i][j] = (fx4){0.f,0.f,0.f,0.f};
  run_gemm(
    [&](int mi,int ks)->bf16x8{ return *(const bf16x8*)(Al + swz(wm*64+mi*16+lr, (ks*32+lk)*2)); },
    [&](int ni,int ks)->bf16x8{ return *(const bf16x8*)(out_w_bf + (size_t)(wn*64+ni*16+lr)*128 + ks*32+lk); },
    acc);
  #pragma unroll
  for (int mi=0;mi<4;mi++)
    #pragma unroll
    for (int ni=0;ni<4;ni++){
      int j = wn*64 + ni*16 + lr, w0 = wm*64 + mi*16 + ld4;
      float bj = out_b[j];
      fx4 o = acc[mi][ni];
      o[0]+=bj; o[1]+=bj; o[2]+=bj; o[3]+=bj;
      *(fx4*)(out + ((size_t)(b*128 + j)*128 + h)*128 + w0) = o;
    }
}

extern "C" void kernel_launch(void* const* d_in, const int* in_sizes, int n_in,
                              void* d_out, int out_size, void* d_ws, size_t ws_size,
                              hipStream_t stream)
{
  const float* x      = (const float*)d_in[0];
  const float* dw_w   = (const float*)d_in[1];
  const float* dw_b   = (const float*)d_in[2];
  const float* in_w   = (const float*)d_in[3];
  const float* in_b   = (const float*)d_in[4];
  const float* out_w  = (const float*)d_in[5];
  const float* out_b  = (const float*)d_in[6];
  const float* ln_w   = (const float*)d_in[7];
  const float* ln_b   = (const float*)d_in[8];
  const float* ph_w   = (const float*)d_in[9];
  const float* ph_b   = (const float*)d_in[10];
  const float* wsp    = (const float*)d_in[11];
  const float* dmp    = (const float*)d_in[12];
  const float* fe     = (const float*)d_in[13];
  float* outp = (float*)d_out;

  float* modT  = (float*)d_ws;                 // 2,097,152 f32, [c][w-freq][h-freq]
  float* projT = modT + 2097152;               // 2,097,152 f32
  unsigned short* feb      = (unsigned short*)(projT + 2097152);  // 2,097,152 bf16
  unsigned short* conv     = feb     + 2097152;
  unsigned short* carrier  = conv    + 16777216;
  unsigned short* gate     = carrier + 16777216;
  unsigned short* fusedb   = gate    + 16777216;
  unsigned short* basis_bf = fusedb  + 16777216;
  unsigned short* basisT_bf= basis_bf + 16384;
  unsigned short* in_w_bf  = basisT_bf + 16384;
  unsigned short* out_w_bf = in_w_bf + 32768;
  unsigned short* ph_w_bf  = out_w_bf + 16384;

  prep_kernel<<<128,128,0,stream>>>(in_w, ph_w, out_w, basis_bf, basisT_bf, ph_w_bf, in_w_bf, out_w_bf);
  castfe_kernel<<<1024,256,0,stream>>>(fe, feb);
  projk_kernel<<<128,256,0,stream>>>(feb, ph_w_bf, projT);
  modfin_kernel<<<2048,256,0,stream>>>(projT, ph_b, wsp, dmp, modT);
  dwconv_kernel<<<4096,256,0,stream>>>(x, dw_w, dw_b, conv);
  inproj_kernel<<<1024,512,0,stream>>>(conv, in_w_bf, in_b, carrier, gate);
  wave_kernel<<<1024,256,0,stream>>>(carrier, basis_bf, basisT_bf, modT, fusedb);
  final_kernel<<<1024,256,0,stream>>>(fusedb, gate, out_w_bf, out_b, ln_w, ln_b, outp);
}

// Round 10
// 171.894 us; speedup vs baseline: 1.1688x; 1.0559x over previous
//
#include <hip/hip_runtime.h>
#include <math.h>

#ifndef M_PI
#define M_PI 3.14159265358979323846
#endif

typedef float fx4 __attribute__((ext_vector_type(4)));
typedef __bf16 bf16x8 __attribute__((ext_vector_type(8)));
typedef __bf16 bf16x4 __attribute__((ext_vector_type(4)));

__device__ __forceinline__ unsigned short f2bf(float f){
  union { float f; unsigned u; } v; v.f = f;
  unsigned r = v.u + 0x7FFFu + ((v.u >> 16) & 1u);
  return (unsigned short)(r >> 16);
}
__device__ __forceinline__ float bf2f(unsigned short u){
  union { unsigned u; float f; } v; v.u = ((unsigned)u) << 16;
  return v.f;
}
// swizzled byte offset within a [row][128] bf16 tile (256 B rows)
__device__ __forceinline__ int swz(int row, int colbyte){
  return row*256 + (colbyte ^ ((row & 7) << 4));
}

// Double-buffered 128-deep (per-wave 64x64) MFMA GEMM core.
template<typename FA, typename FB>
__device__ __forceinline__ void run_gemm(FA la, FB lb, fx4 (&acc)[4][4]){
  bf16x8 a[2][4], b[2][4];
  #pragma unroll
  for (int mi=0;mi<4;mi++){ a[0][mi]=la(mi,0); b[0][mi]=lb(mi,0); }
  #pragma unroll
  for (int ks=0; ks<4; ks++){
    int cur = ks&1, nxt = cur^1;
    if (ks<3){
      #pragma unroll
      for (int mi=0;mi<4;mi++){ a[nxt][mi]=la(mi,ks+1); b[nxt][mi]=lb(mi,ks+1); }
    }
    #pragma unroll
    for (int mi=0;mi<4;mi++)
      #pragma unroll
      for (int ni=0;ni<4;ni++)
        acc[mi][ni] = __builtin_amdgcn_mfma_f32_16x16x32_bf16(a[cur][mi], b[cur][ni], acc[mi][ni], 0, 0, 0);
  }
}

// Two-slice pair, shared B operand: acc0 = A0*B, acc1 = A1*B.
template<typename FA0, typename FA1, typename FB>
__device__ __forceinline__ void run_pair_sharedB(FA0 la0, FA1 la1, FB lb,
                                                 fx4 (&acc0)[4][4], fx4 (&acc1)[4][4]){
  bf16x8 a0[2][4], a1[2][4], b[2][4];
  #pragma unroll
  for (int mi=0;mi<4;mi++){ a0[0][mi]=la0(mi,0); a1[0][mi]=la1(mi,0); b[0][mi]=lb(mi,0); }
  #pragma unroll
  for (int ks=0; ks<4; ks++){
    int cur = ks&1, nxt = cur^1;
    if (ks<3){
      #pragma unroll
      for (int mi=0;mi<4;mi++){ a0[nxt][mi]=la0(mi,ks+1); a1[nxt][mi]=la1(mi,ks+1); b[nxt][mi]=lb(mi,ks+1); }
    }
    #pragma unroll
    for (int mi=0;mi<4;mi++)
      #pragma unroll
      for (int ni=0;ni<4;ni++){
        acc0[mi][ni] = __builtin_amdgcn_mfma_f32_16x16x32_bf16(a0[cur][mi], b[cur][ni], acc0[mi][ni], 0, 0, 0);
        acc1[mi][ni] = __builtin_amdgcn_mfma_f32_16x16x32_bf16(a1[cur][mi], b[cur][ni], acc1[mi][ni], 0, 0, 0);
      }
  }
}

// Two-slice pair, shared A operand: acc0 = A*B0, acc1 = A*B1.
template<typename FA, typename FB0, typename FB1>
__device__ __forceinline__ void run_pair_sharedA(FA la, FB0 lb0, FB1 lb1,
                                                 fx4 (&acc0)[4][4], fx4 (&acc1)[4][4]){
  bf16x8 a[2][4], b0[2][4], b1[2][4];
  #pragma unroll
  for (int mi=0;mi<4;mi++){ a[0][mi]=la(mi,0); b0[0][mi]=lb0(mi,0); b1[0][mi]=lb1(mi,0); }
  #pragma unroll
  for (int ks=0; ks<4; ks++){
    int cur = ks&1, nxt = cur^1;
    if (ks<3){
      #pragma unroll
      for (int mi=0;mi<4;mi++){ a[nxt][mi]=la(mi,ks+1); b0[nxt][mi]=lb0(mi,ks+1); b1[nxt][mi]=lb1(mi,ks+1); }
    }
    #pragma unroll
    for (int mi=0;mi<4;mi++)
      #pragma unroll
      for (int ni=0;ni<4;ni++){
        acc0[mi][ni] = __builtin_amdgcn_mfma_f32_16x16x32_bf16(a[cur][mi], b0[cur][ni], acc0[mi][ni], 0, 0, 0);
        acc1[mi][ni] = __builtin_amdgcn_mfma_f32_16x16x32_bf16(a[cur][mi], b1[cur][ni], acc1[mi][ni], 0, 0, 0);
      }
  }
}

// ---------------- prep: DCT basis (bf16) + weight casts ----------------
__global__ __launch_bounds__(128) void prep_kernel(
    const float* __restrict__ in_w, const float* __restrict__ ph_w,
    const float* __restrict__ out_w,
    unsigned short* __restrict__ basis_bf, unsigned short* __restrict__ basisT_bf,
    unsigned short* __restrict__ ph_w_bf, unsigned short* __restrict__ in_w_bf,
    unsigned short* __restrict__ out_w_bf)
{
  int n = blockIdx.x;     // freq
  int h = threadIdx.x;    // pos
  double arg = (double)(n*(2*h+1)) * (M_PI/256.0);
  double v = cos(arg) * 0.125;           // sqrt(2/128) = 0.125
  if (n==0) v *= 0.7071067811865476;
  unsigned short bv = f2bf((float)v);
  basis_bf[n*128+h]  = bv;
  basisT_bf[h*128+n] = bv;
  ph_w_bf[n*128+h]  = f2bf(ph_w[n*128+h]);
  in_w_bf[n*128+h]        = f2bf(in_w[n*128+h]);
  in_w_bf[(n+128)*128+h]  = f2bf(in_w[(n+128)*128+h]);
  out_w_bf[n*128+h]       = f2bf(out_w[n*128+h]);
}

// ---------------- cast freq_embed fp32 -> bf16, flat ----------------
__global__ __launch_bounds__(256) void castfe_kernel(
  const float* __restrict__ fe, unsigned short* __restrict__ feb)
{
  int idx = blockIdx.x*256 + threadIdx.x;     // 262144 threads, 8 floats each
  const float* s = fe + (size_t)idx*8;
  float4 f0 = *(const float4*)s;
  float4 f1 = *(const float4*)(s+4);
  unsigned short o[8];
  o[0]=f2bf(f0.x); o[1]=f2bf(f0.y); o[2]=f2bf(f0.z); o[3]=f2bf(f0.w);
  o[4]=f2bf(f1.x); o[5]=f2bf(f1.y); o[6]=f2bf(f1.z); o[7]=f2bf(f1.w);
  *(int4*)(feb + (size_t)idx*8) = *(const int4*)o;
}

// ---------------- projk: proj = feb[16384,128] @ ph_w^T -> projT[c][r] fp32 ----------------
__global__ __launch_bounds__(256) void projk_kernel(
  const unsigned short* __restrict__ feb, const unsigned short* __restrict__ ph_w_bf,
  float* __restrict__ projT)
{
  int r0 = blockIdx.x * 128;
  int t = threadIdx.x;
  int l = t & 63, wid = t >> 6;
  int wm = wid >> 1, wn = wid & 1;
  int lr = l & 15, lk = (l>>4)*8, ld4 = (l>>4)*4;
  fx4 acc[4][4];
  #pragma unroll
  for (int i=0;i<4;i++) for (int j=0;j<4;j++) acc[i][j] = (fx4){0.f,0.f,0.f,0.f};
  run_gemm(
    [&](int mi,int ks)->bf16x8{ return *(const bf16x8*)(feb + (size_t)(r0 + wm*64+mi*16+lr)*128 + ks*32+lk); },
    [&](int ni,int ks)->bf16x8{ return *(const bf16x8*)(ph_w_bf + (size_t)(wn*64+ni*16+lr)*128 + ks*32+lk); },
    acc);
  #pragma unroll
  for (int mi=0;mi<4;mi++)
    #pragma unroll
    for (int ni=0;ni<4;ni++){
      int c = wn*64 + ni*16 + lr;
      int r = r0 + wm*64 + mi*16 + ld4;
      *(fx4*)(projT + (size_t)c*16384 + r) = acc[mi][ni];
    }
}

// ---------------- modfin: factor -> modT[c][q][p]  (q = fe-col = freq-w, p = fe-row = freq-h)
__global__ __launch_bounds__(256) void modfin_kernel(
  const float* __restrict__ projT, const float* __restrict__ ph_b,
  const float* __restrict__ wave_speed, const float* __restrict__ damping,
  float* __restrict__ modT)
{
  int blk = blockIdx.x;
  int c = blk >> 4, qb = blk & 15;
  int t = threadIdx.x;
  int q = qb*8 + (t>>5);
  int p0 = (t & 31)*4;
  float ws0 = wave_speed[0];
  float dmp = damping[0];
  float inv = 1.0f / fmaxf(fabsf(ws0), 1e-6f);
  float dampf = 1.0f + 0.5f*dmp;
  float bc = ph_b[c];
  const float* src = projT + (size_t)c*16384 + q;
  float o[4];
  #pragma unroll
  for (int i=0;i<4;i++){
    float v = src[(size_t)(p0+i)*128] + bc;
    float g = 0.5f*v*(1.0f + erff(v*0.70710678118f));
    float wp = ws0*g;
    o[i] = __cosf(wp) + __sinf(wp)*inv*dampf;
  }
  *(float4*)(modT + ((size_t)c*128 + q)*128 + p0) = make_float4(o[0],o[1],o[2],o[3]);
}

// ---------------- depthwise 3x3 conv, NCHW fp32 -> NCHW bf16 (rolling-row, shfl halo) ----
__global__ __launch_bounds__(256) void dwconv_kernel(
  const float* __restrict__ x, const float* __restrict__ dw_w,
  const float* __restrict__ dw_b, unsigned short* __restrict__ conv)
{
  int blk = blockIdx.x;          // plane*4 + band
  int plane = blk >> 2, band = blk & 3;
  int c = plane & 127;
  const float* xp = x + (size_t)plane*16384;
  unsigned short* op = conv + (size_t)plane*16384;
  const float* kw = dw_w + c*9;
  float k0=kw[0],k1=kw[1],k2=kw[2],k3=kw[3],k4=kw[4],k5=kw[5],k6=kw[6],k7=kw[7],k8=kw[8];
  float bias = dw_b[c];
  int t = threadIdx.x;
  int q = t & 31;
  int w0 = q*4;
  int rg = t >> 5;
  int h0 = band*32 + rg*4;       // 4 output rows h0..h0+3
  bool le = (q==0), re = (q==31);

  float4 fA, fB, fC; float lA,rA,lB,rB,lC,rC;
  #define LOADROW(hh, f, l, r) { \
    int hc = (hh)<0 ? 0 : ((hh)>127 ? 127 : (hh)); \
    f = *(const float4*)(xp + hc*128 + w0); \
    float lu = __shfl_up(f.w, 1, 32); \
    float rd = __shfl_down(f.x, 1, 32); \
    l = le ? 0.f : lu; \
    r = re ? 0.f : rd; \
    if ((hh)<0 || (hh)>127){ f = make_float4(0.f,0.f,0.f,0.f); l=0.f; r=0.f; } \
  }
  LOADROW(h0-1, fA,lA,rA);
  LOADROW(h0,   fB,lB,rB);
  #pragma unroll
  for (int i=0;i<4;i++){
    LOADROW(h0+1+i, fC,lC,rC);
    float4 o;
    o.x = bias; o.y = bias; o.z = bias; o.w = bias;
    o.x = fmaf(k0,lA,  fmaf(k1,fA.x, fmaf(k2,fA.y, o.x)));
    o.y = fmaf(k0,fA.x,fmaf(k1,fA.y, fmaf(k2,fA.z, o.y)));
    o.z = fmaf(k0,fA.y,fmaf(k1,fA.z, fmaf(k2,fA.w, o.z)));
    o.w = fmaf(k0,fA.z,fmaf(k1,fA.w, fmaf(k2,rA,   o.w)));
    o.x = fmaf(k3,lB,  fmaf(k4,fB.x, fmaf(k5,fB.y, o.x)));
    o.y = fmaf(k3,fB.x,fmaf(k4,fB.y, fmaf(k5,fB.z, o.y)));
    o.z = fmaf(k3,fB.y,fmaf(k4,fB.z, fmaf(k5,fB.w, o.z)));
    o.w = fmaf(k3,fB.z,fmaf(k4,fB.w, fmaf(k5,rB,   o.w)));
    o.x = fmaf(k6,lC,  fmaf(k7,fC.x, fmaf(k8,fC.y, o.x)));
    o.y = fmaf(k6,fC.x,fmaf(k7,fC.y, fmaf(k8,fC.z, o.y)));
    o.z = fmaf(k6,fC.y,fmaf(k7,fC.z, fmaf(k8,fC.w, o.z)));
    o.w = fmaf(k6,fC.z,fmaf(k7,fC.w, fmaf(k8,rC,   o.w)));
    bf16x4 v;
    v[0]=(__bf16)o.x; v[1]=(__bf16)o.y; v[2]=(__bf16)o.z; v[3]=(__bf16)o.w;
    *(bf16x4*)(op + (size_t)(h0+i)*128 + w0) = v;
    fA=fB; lA=lB; rA=rB;
    fB=fC; lB=lC; rB=rC;
  }
  #undef LOADROW
}

// ---------------- in_proj MFMA: per (b,h): [w]x[c] @ in_w^T -> carrier NCHW bf16, silu(gate) BHWC bf16
__global__ __launch_bounds__(512) void inproj_kernel(
  const unsigned short* __restrict__ conv, const unsigned short* __restrict__ in_w_bf,
  const float* __restrict__ in_b, unsigned short* __restrict__ carrier,
  unsigned short* __restrict__ gate)
{
  __shared__ char A[32768];   // [w][c] swizzled bf16; reused as gate transpose buffer
  int blk = blockIdx.x; int b = blk>>7, h = blk&127;
  const unsigned short* C = conv + (size_t)b*2097152 + h*128;  // + c*16384 + w
  int t = threadIdx.x;
  // stage A: transpose conv [c][w] -> LDS [w][c] via 4-channel packs
  {
    int wl = t & 63, grp = t >> 6;   // grp 0..7
    #pragma unroll
    for (int p=0;p<2;p++){
      int w = wl + 64*p;
      #pragma unroll
      for (int q=0;q<4;q++){
        int c0 = (q*8 + grp)*4;
        ushort4 v;
        v.x = C[(size_t)(c0+0)*16384 + w];
        v.y = C[(size_t)(c0+1)*16384 + w];
        v.z = C[(size_t)(c0+2)*16384 + w];
        v.w = C[(size_t)(c0+3)*16384 + w];
        *(ushort4*)(A + swz(w, c0*2)) = v;
      }
    }
  }
  __syncthreads();
  int l = t & 63, wid = t >> 6;
  int wm = wid >> 2, wn = wid & 3;   // 2 x 4 waves, 64x64 quadrants over M=128,N=256
  int lr = l & 15, lk = (l>>4)*8, ld4 = (l>>4)*4;
  fx4 acc[4][4];
  #pragma unroll
  for (int i=0;i<4;i++) for (int j=0;j<4;j++) acc[i][j] = (fx4){0.f,0.f,0.f,0.f};
  run_gemm(
    [&](int mi,int ks)->bf16x8{ return *(const bf16x8*)(A + swz(wm*64+mi*16+lr, (ks*32+lk)*2)); },
    [&](int ni,int ks)->bf16x8{ return *(const bf16x8*)(in_w_bf + (size_t)(wn*64+ni*16+lr)*128 + ks*32+lk); },
    acc);
  __syncthreads();   // done reading A; gate waves will overwrite it
  if (wn < 2){
    // carrier: n in [0,128): store bf16 NCHW, 4 consecutive w per 8B store
    #pragma unroll
    for (int mi=0;mi<4;mi++)
      #pragma unroll
      for (int ni=0;ni<4;ni++){
        int n = wn*64 + ni*16 + lr;
        int w0 = wm*64 + mi*16 + ld4;
        float bias = in_b[n];
        ushort4 v;
        v.x=f2bf(acc[mi][ni][0]+bias); v.y=f2bf(acc[mi][ni][1]+bias);
        v.z=f2bf(acc[mi][ni][2]+bias); v.w=f2bf(acc[mi][ni][3]+bias);
        *(ushort4*)(carrier + (size_t)(b*128+n)*16384 + h*128 + w0) = v;
      }
  } else {
    // gate: n in [128,256): silu, write transposed [w][c] into LDS
    #pragma unroll
    for (int mi=0;mi<4;mi++)
      #pragma unroll
      for (int ni=0;ni<4;ni++){
        int n = wn*64 + ni*16 + lr;     // 128..255
        int c = n - 128;
        int w0 = wm*64 + mi*16 + ld4;
        float bias = in_b[n];
        #pragma unroll
        for (int r=0;r<4;r++){
          float v = acc[mi][ni][r] + bias;
          float s = v / (1.0f + __expf(-v));
          *(unsigned short*)(A + swz(w0+r, c*2)) = f2bf(s);
        }
      }
  }
  __syncthreads();
  // copy gate LDS [w][c] -> global BHWC bf16, coalesced
  {
    unsigned short* gout = gate + (size_t)blk*16384;   // [w][c]
    int w = t >> 2, cq = (t & 3) * 32;
    #pragma unroll
    for (int i=0;i<4;i++){
      int c0 = cq + i*8;
      int4 v = *(const int4*)(A + swz(w, c0*2));
      *(int4*)(gout + w*128 + c0) = v;
    }
  }
}

// ---------------- fused wave kernel: 4 chained MFMA GEMM phases, TWO slices per block ----
// s0 = blk (b in 0..3), s1 = blk+512 (b in 4..7); same c -> shared modT & basis operands.
__global__ __launch_bounds__(256) void wave_kernel(
  const unsigned short* __restrict__ carrier,
  const unsigned short* __restrict__ basis,    // [f][pos] bf16
  const unsigned short* __restrict__ basisT,   // [pos][f] bf16
  const float* __restrict__ modT,              // [c][w-freq][h-freq] fp32
  unsigned short* __restrict__ fused)
{
  __shared__ char U0[32768];
  __shared__ char U1[32768];
  int blk = blockIdx.x;          // 0..511
  int c = blk & 127;
  const unsigned short* X0 = carrier + (size_t)blk*16384;
  const unsigned short* X1 = carrier + (size_t)(blk+512)*16384;
  unsigned short* F0 = fused + (size_t)blk*16384;
  unsigned short* F1 = fused + (size_t)(blk+512)*16384;
  int t = threadIdx.x;
  int l = t & 63, wid = t >> 6;
  int wm = wid >> 1, wn = wid & 1;
  int lr = l & 15, lk = (l>>4)*8, ld4 = (l>>4)*4;
  fx4 acc0[4][4], acc1[4][4];

  #define ZACC { _Pragma("unroll") for (int i=0;i<4;i++) _Pragma("unroll") for (int j=0;j<4;j++){ acc0[i][j]=(fx4){0.f,0.f,0.f,0.f}; acc1[i][j]=(fx4){0.f,0.f,0.f,0.f}; } }
  #define TSTORE(BUF0, BUF1, ROW, COL) { \
    _Pragma("unroll") for (int mi=0;mi<4;mi++) \
      _Pragma("unroll") for (int ni=0;ni<4;ni++){ \
        int rr = wn*64 + ni*16 + lr, cc = wm*64 + mi*16 + ld4; (void)rr; (void)cc; \
        bf16x4 v0, v1; \
        v0[0]=(__bf16)acc0[mi][ni][0]; v0[1]=(__bf16)acc0[mi][ni][1]; \
        v0[2]=(__bf16)acc0[mi][ni][2]; v0[3]=(__bf16)acc0[mi][ni][3]; \
        v1[0]=(__bf16)acc1[mi][ni][0]; v1[1]=(__bf16)acc1[mi][ni][1]; \
        v1[2]=(__bf16)acc1[mi][ni][2]; v1[3]=(__bf16)acc1[mi][ni][3]; \
        *(bf16x4*)(BUF0 + swz(rr, cc*2)) = v0; \
        *(bf16x4*)(BUF1 + swz(rr, cc*2)) = v1; \
      } }

  // G1: D1[h][m] = X @ Bw^T  (A0=X0,A1=X1 rows h; B=basis rows m shared; k=w)
  ZACC;
  run_pair_sharedB(
    [&](int mi,int ks)->bf16x8{ return *(const bf16x8*)(X0 + (size_t)(wm*64+mi*16+lr)*128 + ks*32+lk); },
    [&](int mi,int ks)->bf16x8{ return *(const bf16x8*)(X1 + (size_t)(wm*64+mi*16+lr)*128 + ks*32+lk); },
    [&](int ni,int ks)->bf16x8{ return *(const bf16x8*)(basis + (size_t)(wn*64+ni*16+lr)*128 + ks*32+lk); },
    acc0, acc1);
  TSTORE(U0, U1, m, h);          // U = D1^T : [m][h]
  __syncthreads();               // bar 1: U ready

  // G2: D2[n][m] = Bh @ U^T  (A=basis rows n shared; B0=U0,B1=U1 rows m; k=h), then modulate
  ZACC;
  run_pair_sharedA(
    [&](int mi,int ks)->bf16x8{ return *(const bf16x8*)(basis + (size_t)(wm*64+mi*16+lr)*128 + ks*32+lk); },
    [&](int ni,int ks)->bf16x8{ return *(const bf16x8*)(U0 + swz(wn*64+ni*16+lr, (ks*32+lk)*2)); },
    [&](int ni,int ks)->bf16x8{ return *(const bf16x8*)(U1 + swz(wn*64+ni*16+lr, (ks*32+lk)*2)); },
    acc0, acc1);
  {
    const float* Mc = modT + (size_t)c*16384;
    #pragma unroll
    for (int mi=0;mi<4;mi++)
      #pragma unroll
      for (int ni=0;ni<4;ni++){
        int n0 = wm*64 + mi*16 + ld4, m = wn*64 + ni*16 + lr;
        fx4 mv = *(const fx4*)(Mc + (size_t)m*128 + n0);
        acc0[mi][ni] *= mv;
        acc1[mi][ni] *= mv;
      }
  }
  __syncthreads();               // bar 2: all reads of U done
  TSTORE(U0, U1, m, n);          // U = D2^T : [m][n]
  __syncthreads();               // bar 3: U ready

  // G3: D3[m][h] = U @ Bh  (A0=U0,A1=U1 rows m; B=basisT rows h shared; k=n)
  ZACC;
  run_pair_sharedB(
    [&](int mi,int ks)->bf16x8{ return *(const bf16x8*)(U0 + swz(wm*64+mi*16+lr, (ks*32+lk)*2)); },
    [&](int mi,int ks)->bf16x8{ return *(const bf16x8*)(U1 + swz(wm*64+mi*16+lr, (ks*32+lk)*2)); },
    [&](int ni,int ks)->bf16x8{ return *(const bf16x8*)(basisT + (size_t)(wn*64+ni*16+lr)*128 + ks*32+lk); },
    acc0, acc1);
  __syncthreads();               // bar 4: all reads of U done
  TSTORE(U0, U1, h, m);          // U = D3^T : [h][m]
  __syncthreads();               // bar 5: U ready

  // G4: D4[w][h] = BwT @ U^T  (A=basisT rows w shared; B0=U0,B1=U1 rows h; k=m)
  ZACC;
  run_pair_sharedA(
    [&](int mi,int ks)->bf16x8{ return *(const bf16x8*)(basisT + (size_t)(wm*64+mi*16+lr)*128 + ks*32+lk); },
    [&](int ni,int ks)->bf16x8{ return *(const bf16x8*)(U0 + swz(wn*64+ni*16+lr, (ks*32+lk)*2)); },
    [&](int ni,int ks)->bf16x8{ return *(const bf16x8*)(U1 + swz(wn*64+ni*16+lr, (ks*32+lk)*2)); },
    acc0, acc1);
  // store fused[h][w] bf16: D4[row=w][col=h]
  #pragma unroll
  for (int mi=0;mi<4;mi++)
    #pragma unroll
    for (int ni=0;ni<4;ni++){
      int hh = wn*64 + ni*16 + lr, w0 = wm*64 + mi*16 + ld4;
      bf16x4 v0, v1;
      v0[0]=(__bf16)acc0[mi][ni][0]; v0[1]=(__bf16)acc0[mi][ni][1];
      v0[2]=(__bf16)acc0[mi][ni][2]; v0[3]=(__bf16)acc0[mi][ni][3];
      v1[0]=(__bf16)acc1[mi][ni][0]; v1[1]=(__bf16)acc1[mi][ni][1];
      v1[2]=(__bf16)acc1[mi][ni][2]; v1[3]=(__bf16)acc1[mi][ni][3];
      *(bf16x4*)(F0 + hh*128 + w0) = v0;
      *(bf16x4*)(F1 + hh*128 + w0) = v1;
    }
  #undef ZACC
  #undef TSTORE
}

// ---------------- final: LN * silu(gate) @ out_w^T + b -> out NCHW fp32 ----------------
__global__ __launch_bounds__(256) void final_kernel(
  const unsigned short* __restrict__ fused, const unsigned short* __restrict__ gate,
  const unsigned short* __restrict__ out_w_bf, const float* __restrict__ out_b,
  const float* __restrict__ ln_w, const float* __restrict__ ln_b,
  float* __restrict__ out)
{
  __shared__ char Fl[32768];   // F [c][w] swizzled bf16
  __shared__ char Al[32768];   // act [w][c] swizzled bf16
  __shared__ float red[256], red2[256];
  __shared__ float mu[128], rs[128];
  int blk = blockIdx.x; int b = blk>>7, h = blk&127;
  const unsigned short* Fsrc = fused + (size_t)b*2097152 + h*128;  // + c*16384 + w
  const unsigned short* G = gate + (size_t)blk*16384;              // [w][c]
  int t = threadIdx.x;
  // stage F [c][w]
  {
    int c = t>>1, wq = (t&1)*64;
    #pragma unroll
    for (int i=0;i<8;i++){
      int w0 = wq + i*8;
      int4 v = *(const int4*)(Fsrc + (size_t)c*16384 + w0);
      *(int4*)(Fl + swz(c, w0*2)) = v;
    }
  }
  __syncthreads();
  // LN stats per w (reduce over c)
  {
    int w = t&127, half = t>>7;
    float s=0.f, q=0.f;
    for (int i=0;i<64;i++){
      int c = half*64 + i;
      float f = bf2f(*(const unsigned short*)(Fl + swz(c, w*2)));
      s += f; q = fmaf(f,f,q);
    }
    red[t]=s; red2[t]=q;
  }
  __syncthreads();
  if (t < 128){
    float ss = red[t]+red[t+128], qq = red2[t]+red2[t+128];
    float m = ss*(1.f/128.f);
    float var = qq*(1.f/128.f) - m*m;
    mu[t]=m; rs[t]=rsqrtf(var+1e-5f);
  }
  __syncthreads();
  // act[w][c] = LN(F)*silu_gate
  {
    int w = t>>1, cq = (t&1)*64;
    float m_ = mu[w], r_ = rs[w];
    #pragma unroll
    for (int i=0;i<8;i++){
      int c0 = cq + i*8;
      ushort4 g0 = *(const ushort4*)(G + (size_t)w*128 + c0);
      ushort4 g1 = *(const ushort4*)(G + (size_t)w*128 + c0 + 4);
      unsigned short ov[8];
      unsigned short gv[8] = {g0.x,g0.y,g0.z,g0.w,g1.x,g1.y,g1.z,g1.w};
      #pragma unroll
      for (int j=0;j<8;j++){
        int cc = c0+j;
        float f = bf2f(*(const unsigned short*)(Fl + swz(cc, w*2)));
        float a = fmaf((f-m_)*r_, ln_w[cc], ln_b[cc]) * bf2f(gv[j]);
        ov[j] = f2bf(a);
      }
      *(int4*)(Al + swz(w, c0*2)) = *(const int4*)ov;
    }
  }
  __syncthreads();
  // MFMA: D[w][j] = act @ out_w^T
  int l = t & 63, wid = t >> 6;
  int wm = wid >> 1, wn = wid & 1;
  int lr = l & 15, lk = (l>>4)*8, ld4 = (l>>4)*4;
  fx4 acc[4][4];
  #pragma unroll
  for (int i=0;i<4;i++) for (int j=0;j<4;j++) acc[i][j] = (fx4){0.f,0.f,0.f,0.f};
  run_gemm(
    [&](int mi,int ks)->bf16x8{ return *(const bf16x8*)(Al + swz(wm*64+mi*16+lr, (ks*32+lk)*2)); },
    [&](int ni,int ks)->bf16x8{ return *(const bf16x8*)(out_w_bf + (size_t)(wn*64+ni*16+lr)*128 + ks*32+lk); },
    acc);
  #pragma unroll
  for (int mi=0;mi<4;mi++)
    #pragma unroll
    for (int ni=0;ni<4;ni++){
      int j = wn*64 + ni*16 + lr, w0 = wm*64 + mi*16 + ld4;
      float bj = out_b[j];
      fx4 o = acc[mi][ni];
      o[0]+=bj; o[1]+=bj; o[2]+=bj; o[3]+=bj;
      *(fx4*)(out + ((size_t)(b*128 + j)*128 + h)*128 + w0) = o;
    }
}

extern "C" void kernel_launch(void* const* d_in, const int* in_sizes, int n_in,
                              void* d_out, int out_size, void* d_ws, size_t ws_size,
                              hipStream_t stream)
{
  const float* x      = (const float*)d_in[0];
  const float* dw_w   = (const float*)d_in[1];
  const float* dw_b   = (const float*)d_in[2];
  const float* in_w   = (const float*)d_in[3];
  const float* in_b   = (const float*)d_in[4];
  const float* out_w  = (const float*)d_in[5];
  const float* out_b  = (const float*)d_in[6];
  const float* ln_w   = (const float*)d_in[7];
  const float* ln_b   = (const float*)d_in[8];
  const float* ph_w   = (const float*)d_in[9];
  const float* ph_b   = (const float*)d_in[10];
  const float* wsp    = (const float*)d_in[11];
  const float* dmp    = (const float*)d_in[12];
  const float* fe     = (const float*)d_in[13];
  float* outp = (float*)d_out;

  float* modT  = (float*)d_ws;                 // 2,097,152 f32, [c][w-freq][h-freq]
  float* projT = modT + 2097152;               // 2,097,152 f32
  unsigned short* feb      = (unsigned short*)(projT + 2097152);  // 2,097,152 bf16
  unsigned short* conv     = feb     + 2097152;
  unsigned short* carrier  = conv    + 16777216;
  unsigned short* gate     = carrier + 16777216;
  unsigned short* fusedb   = gate    + 16777216;
  unsigned short* basis_bf = fusedb  + 16777216;
  unsigned short* basisT_bf= basis_bf + 16384;
  unsigned short* in_w_bf  = basisT_bf + 16384;
  unsigned short* out_w_bf = in_w_bf + 32768;
  unsigned short* ph_w_bf  = out_w_bf + 16384;

  prep_kernel<<<128,128,0,stream>>>(in_w, ph_w, out_w, basis_bf, basisT_bf, ph_w_bf, in_w_bf, out_w_bf);
  castfe_kernel<<<1024,256,0,stream>>>(fe, feb);
  projk_kernel<<<128,256,0,stream>>>(feb, ph_w_bf, projT);
  modfin_kernel<<<2048,256,0,stream>>>(projT, ph_b, wsp, dmp, modT);
  dwconv_kernel<<<4096,256,0,stream>>>(x, dw_w, dw_b, conv);
  inproj_kernel<<<1024,512,0,stream>>>(conv, in_w_bf, in_b, carrier, gate);
  wave_kernel<<<512,256,0,stream>>>(carrier, basis_bf, basisT_bf, modT, fusedb);
  final_kernel<<<1024,256,0,stream>>>(fusedb, gate, out_w_bf, out_b, ln_w, ln_b, outp);
}

// Round 11
// 171.761 us; speedup vs baseline: 1.1697x; 1.0008x over previous
//
#include <hip/hip_runtime.h>
#include <math.h>

#ifndef M_PI
#define M_PI 3.14159265358979323846
#endif

typedef float fx4 __attribute__((ext_vector_type(4)));
typedef __bf16 bf16x8 __attribute__((ext_vector_type(8)));
typedef __bf16 bf16x4 __attribute__((ext_vector_type(4)));

__device__ __forceinline__ unsigned short f2bf(float f){
  union { float f; unsigned u; } v; v.f = f;
  unsigned r = v.u + 0x7FFFu + ((v.u >> 16) & 1u);
  return (unsigned short)(r >> 16);
}
__device__ __forceinline__ float bf2f(unsigned short u){
  union { unsigned u; float f; } v; v.u = ((unsigned)u) << 16;
  return v.f;
}
// swizzled byte offset within a [row][128] bf16 tile (256 B rows)
__device__ __forceinline__ int swz(int row, int colbyte){
  return row*256 + (colbyte ^ ((row & 7) << 4));
}

// Double-buffered 128-deep (per-wave 64x64) MFMA GEMM core.
template<typename FA, typename FB>
__device__ __forceinline__ void run_gemm(FA la, FB lb, fx4 (&acc)[4][4]){
  bf16x8 a[2][4], b[2][4];
  #pragma unroll
  for (int mi=0;mi<4;mi++){ a[0][mi]=la(mi,0); b[0][mi]=lb(mi,0); }
  #pragma unroll
  for (int ks=0; ks<4; ks++){
    int cur = ks&1, nxt = cur^1;
    if (ks<3){
      #pragma unroll
      for (int mi=0;mi<4;mi++){ a[nxt][mi]=la(mi,ks+1); b[nxt][mi]=lb(mi,ks+1); }
    }
    #pragma unroll
    for (int mi=0;mi<4;mi++)
      #pragma unroll
      for (int ni=0;ni<4;ni++)
        acc[mi][ni] = __builtin_amdgcn_mfma_f32_16x16x32_bf16(a[cur][mi], b[cur][ni], acc[mi][ni], 0, 0, 0);
  }
}

// Two-slice pair, shared B operand: acc0 = A0*B, acc1 = A1*B.
template<typename FA0, typename FA1, typename FB>
__device__ __forceinline__ void run_pair_sharedB(FA0 la0, FA1 la1, FB lb,
                                                 fx4 (&acc0)[4][4], fx4 (&acc1)[4][4]){
  bf16x8 a0[2][4], a1[2][4], b[2][4];
  #pragma unroll
  for (int mi=0;mi<4;mi++){ a0[0][mi]=la0(mi,0); a1[0][mi]=la1(mi,0); b[0][mi]=lb(mi,0); }
  #pragma unroll
  for (int ks=0; ks<4; ks++){
    int cur = ks&1, nxt = cur^1;
    if (ks<3){
      #pragma unroll
      for (int mi=0;mi<4;mi++){ a0[nxt][mi]=la0(mi,ks+1); a1[nxt][mi]=la1(mi,ks+1); b[nxt][mi]=lb(mi,ks+1); }
    }
    #pragma unroll
    for (int mi=0;mi<4;mi++)
      #pragma unroll
      for (int ni=0;ni<4;ni++){
        acc0[mi][ni] = __builtin_amdgcn_mfma_f32_16x16x32_bf16(a0[cur][mi], b[cur][ni], acc0[mi][ni], 0, 0, 0);
        acc1[mi][ni] = __builtin_amdgcn_mfma_f32_16x16x32_bf16(a1[cur][mi], b[cur][ni], acc1[mi][ni], 0, 0, 0);
      }
  }
}

// Two-slice pair, shared A operand: acc0 = A*B0, acc1 = A*B1.
template<typename FA, typename FB0, typename FB1>
__device__ __forceinline__ void run_pair_sharedA(FA la, FB0 lb0, FB1 lb1,
                                                 fx4 (&acc0)[4][4], fx4 (&acc1)[4][4]){
  bf16x8 a[2][4], b0[2][4], b1[2][4];
  #pragma unroll
  for (int mi=0;mi<4;mi++){ a[0][mi]=la(mi,0); b0[0][mi]=lb0(mi,0); b1[0][mi]=lb1(mi,0); }
  #pragma unroll
  for (int ks=0; ks<4; ks++){
    int cur = ks&1, nxt = cur^1;
    if (ks<3){
      #pragma unroll
      for (int mi=0;mi<4;mi++){ a[nxt][mi]=la(mi,ks+1); b0[nxt][mi]=lb0(mi,ks+1); b1[nxt][mi]=lb1(mi,ks+1); }
    }
    #pragma unroll
    for (int mi=0;mi<4;mi++)
      #pragma unroll
      for (int ni=0;ni<4;ni++){
        acc0[mi][ni] = __builtin_amdgcn_mfma_f32_16x16x32_bf16(a[cur][mi], b0[cur][ni], acc0[mi][ni], 0, 0, 0);
        acc1[mi][ni] = __builtin_amdgcn_mfma_f32_16x16x32_bf16(a[cur][mi], b1[cur][ni], acc1[mi][ni], 0, 0, 0);
      }
  }
}

// ---------------- prep: DCT basis (bf16) + weight casts ----------------
__global__ __launch_bounds__(128) void prep_kernel(
    const float* __restrict__ in_w, const float* __restrict__ ph_w,
    const float* __restrict__ out_w,
    unsigned short* __restrict__ basis_bf, unsigned short* __restrict__ basisT_bf,
    unsigned short* __restrict__ ph_w_bf, unsigned short* __restrict__ in_w_bf,
    unsigned short* __restrict__ out_w_bf)
{
  int n = blockIdx.x;     // freq
  int h = threadIdx.x;    // pos
  double arg = (double)(n*(2*h+1)) * (M_PI/256.0);
  double v = cos(arg) * 0.125;           // sqrt(2/128) = 0.125
  if (n==0) v *= 0.7071067811865476;
  unsigned short bv = f2bf((float)v);
  basis_bf[n*128+h]  = bv;
  basisT_bf[h*128+n] = bv;
  ph_w_bf[n*128+h]  = f2bf(ph_w[n*128+h]);
  in_w_bf[n*128+h]        = f2bf(in_w[n*128+h]);
  in_w_bf[(n+128)*128+h]  = f2bf(in_w[(n+128)*128+h]);
  out_w_bf[n*128+h]       = f2bf(out_w[n*128+h]);
}

// ---------------- cast freq_embed fp32 -> bf16, flat ----------------
__global__ __launch_bounds__(256) void castfe_kernel(
  const float* __restrict__ fe, unsigned short* __restrict__ feb)
{
  int idx = blockIdx.x*256 + threadIdx.x;     // 262144 threads, 8 floats each
  const float* s = fe + (size_t)idx*8;
  float4 f0 = *(const float4*)s;
  float4 f1 = *(const float4*)(s+4);
  unsigned short o[8];
  o[0]=f2bf(f0.x); o[1]=f2bf(f0.y); o[2]=f2bf(f0.z); o[3]=f2bf(f0.w);
  o[4]=f2bf(f1.x); o[5]=f2bf(f1.y); o[6]=f2bf(f1.z); o[7]=f2bf(f1.w);
  *(int4*)(feb + (size_t)idx*8) = *(const int4*)o;
}

// ---------------- projk: proj = feb[16384,128] @ ph_w^T -> projT[c][r] fp32 ----------------
__global__ __launch_bounds__(256) void projk_kernel(
  const unsigned short* __restrict__ feb, const unsigned short* __restrict__ ph_w_bf,
  float* __restrict__ projT)
{
  int r0 = blockIdx.x * 128;
  int t = threadIdx.x;
  int l = t & 63, wid = t >> 6;
  int wm = wid >> 1, wn = wid & 1;
  int lr = l & 15, lk = (l>>4)*8, ld4 = (l>>4)*4;
  fx4 acc[4][4];
  #pragma unroll
  for (int i=0;i<4;i++) for (int j=0;j<4;j++) acc[i][j] = (fx4){0.f,0.f,0.f,0.f};
  run_gemm(
    [&](int mi,int ks)->bf16x8{ return *(const bf16x8*)(feb + (size_t)(r0 + wm*64+mi*16+lr)*128 + ks*32+lk); },
    [&](int ni,int ks)->bf16x8{ return *(const bf16x8*)(ph_w_bf + (size_t)(wn*64+ni*16+lr)*128 + ks*32+lk); },
    acc);
  #pragma unroll
  for (int mi=0;mi<4;mi++)
    #pragma unroll
    for (int ni=0;ni<4;ni++){
      int c = wn*64 + ni*16 + lr;
      int r = r0 + wm*64 + mi*16 + ld4;
      *(fx4*)(projT + (size_t)c*16384 + r) = acc[mi][ni];
    }
}

// ---------------- modfin: factor -> modT[c][q][p]  (q = fe-col = freq-w, p = fe-row = freq-h)
__global__ __launch_bounds__(256) void modfin_kernel(
  const float* __restrict__ projT, const float* __restrict__ ph_b,
  const float* __restrict__ wave_speed, const float* __restrict__ damping,
  float* __restrict__ modT)
{
  int blk = blockIdx.x;
  int c = blk >> 4, qb = blk & 15;
  int t = threadIdx.x;
  int q = qb*8 + (t>>5);
  int p0 = (t & 31)*4;
  float ws0 = wave_speed[0];
  float dmp = damping[0];
  float inv = 1.0f / fmaxf(fabsf(ws0), 1e-6f);
  float dampf = 1.0f + 0.5f*dmp;
  float bc = ph_b[c];
  const float* src = projT + (size_t)c*16384 + q;
  float o[4];
  #pragma unroll
  for (int i=0;i<4;i++){
    float v = src[(size_t)(p0+i)*128] + bc;
    float g = 0.5f*v*(1.0f + erff(v*0.70710678118f));
    float wp = ws0*g;
    o[i] = __cosf(wp) + __sinf(wp)*inv*dampf;
  }
  *(float4*)(modT + ((size_t)c*128 + q)*128 + p0) = make_float4(o[0],o[1],o[2],o[3]);
}

// ---------------- depthwise 3x3 conv, NCHW fp32 -> NCHW bf16 (rolling-row, shfl halo) ----
__global__ __launch_bounds__(256) void dwconv_kernel(
  const float* __restrict__ x, const float* __restrict__ dw_w,
  const float* __restrict__ dw_b, unsigned short* __restrict__ conv)
{
  int blk = blockIdx.x;          // plane*4 + band
  int plane = blk >> 2, band = blk & 3;
  int c = plane & 127;
  const float* xp = x + (size_t)plane*16384;
  unsigned short* op = conv + (size_t)plane*16384;
  const float* kw = dw_w + c*9;
  float k0=kw[0],k1=kw[1],k2=kw[2],k3=kw[3],k4=kw[4],k5=kw[5],k6=kw[6],k7=kw[7],k8=kw[8];
  float bias = dw_b[c];
  int t = threadIdx.x;
  int q = t & 31;
  int w0 = q*4;
  int rg = t >> 5;
  int h0 = band*32 + rg*4;       // 4 output rows h0..h0+3
  bool le = (q==0), re = (q==31);

  float4 fA, fB, fC; float lA,rA,lB,rB,lC,rC;
  #define LOADROW(hh, f, l, r) { \
    int hc = (hh)<0 ? 0 : ((hh)>127 ? 127 : (hh)); \
    f = *(const float4*)(xp + hc*128 + w0); \
    float lu = __shfl_up(f.w, 1, 32); \
    float rd = __shfl_down(f.x, 1, 32); \
    l = le ? 0.f : lu; \
    r = re ? 0.f : rd; \
    if ((hh)<0 || (hh)>127){ f = make_float4(0.f,0.f,0.f,0.f); l=0.f; r=0.f; } \
  }
  LOADROW(h0-1, fA,lA,rA);
  LOADROW(h0,   fB,lB,rB);
  #pragma unroll
  for (int i=0;i<4;i++){
    LOADROW(h0+1+i, fC,lC,rC);
    float4 o;
    o.x = bias; o.y = bias; o.z = bias; o.w = bias;
    o.x = fmaf(k0,lA,  fmaf(k1,fA.x, fmaf(k2,fA.y, o.x)));
    o.y = fmaf(k0,fA.x,fmaf(k1,fA.y, fmaf(k2,fA.z, o.y)));
    o.z = fmaf(k0,fA.y,fmaf(k1,fA.z, fmaf(k2,fA.w, o.z)));
    o.w = fmaf(k0,fA.z,fmaf(k1,fA.w, fmaf(k2,rA,   o.w)));
    o.x = fmaf(k3,lB,  fmaf(k4,fB.x, fmaf(k5,fB.y, o.x)));
    o.y = fmaf(k3,fB.x,fmaf(k4,fB.y, fmaf(k5,fB.z, o.y)));
    o.z = fmaf(k3,fB.y,fmaf(k4,fB.z, fmaf(k5,fB.w, o.z)));
    o.w = fmaf(k3,fB.z,fmaf(k4,fB.w, fmaf(k5,rB,   o.w)));
    o.x = fmaf(k6,lC,  fmaf(k7,fC.x, fmaf(k8,fC.y, o.x)));
    o.y = fmaf(k6,fC.x,fmaf(k7,fC.y, fmaf(k8,fC.z, o.y)));
    o.z = fmaf(k6,fC.y,fmaf(k7,fC.z, fmaf(k8,fC.w, o.z)));
    o.w = fmaf(k6,fC.z,fmaf(k7,fC.w, fmaf(k8,rC,   o.w)));
    bf16x4 v;
    v[0]=(__bf16)o.x; v[1]=(__bf16)o.y; v[2]=(__bf16)o.z; v[3]=(__bf16)o.w;
    *(bf16x4*)(op + (size_t)(h0+i)*128 + w0) = v;
    fA=fB; lA=lB; rA=rB;
    fB=fC; lB=lC; rB=rC;
  }
  #undef LOADROW
}

// ---------------- in_proj MFMA: per (b,h): [w]x[c] @ in_w^T -> carrier NCHW bf16, silu(gate) BHWC bf16
// Staging v2: coalesced [c][w] row loads into L1, then LDS-internal transpose into A.
__global__ __launch_bounds__(512) void inproj_kernel(
  const unsigned short* __restrict__ conv, const unsigned short* __restrict__ in_w_bf,
  const float* __restrict__ in_b, unsigned short* __restrict__ carrier,
  unsigned short* __restrict__ gate)
{
  __shared__ char L1[32768];  // conv rows [c][w], swizzled swz(c, w*2)
  __shared__ char A[32768];   // transposed [w][c], swizzled swz(w, c*2); reused for gate out
  int blk = blockIdx.x; int b = blk>>7, h = blk&127;
  const unsigned short* C = conv + (size_t)b*2097152 + h*128;  // + c*16384 + w
  int t = threadIdx.x;
  // stage 1: coalesced int4 row loads [c][w] -> L1
  {
    int w8 = (t & 15) * 8;      // 16 chunks of 8 w
    int cb = t >> 4;            // 0..31
    #pragma unroll
    for (int i=0;i<4;i++){
      int c = cb + i*32;
      int4 v = *(const int4*)(C + (size_t)c*16384 + w8);
      *(int4*)(L1 + swz(c, w8*2)) = v;
    }
  }
  __syncthreads();
  // stage 2: LDS transpose L1[c][w] -> A[w][c]
  {
    int w = t & 127;
    int cb = (t >> 7) * 32;     // 4 groups x 32 c
    #pragma unroll
    for (int i=0;i<4;i++){
      int c0 = cb + i*8;
      unsigned short tmp[8];
      #pragma unroll
      for (int j=0;j<8;j++)
        tmp[j] = *(const unsigned short*)(L1 + swz(c0+j, w*2));
      *(int4*)(A + swz(w, c0*2)) = *(const int4*)tmp;
    }
  }
  __syncthreads();
  int l = t & 63, wid = t >> 6;
  int wm = wid >> 2, wn = wid & 3;   // 2 x 4 waves, 64x64 quadrants over M=128,N=256
  int lr = l & 15, lk = (l>>4)*8, ld4 = (l>>4)*4;
  fx4 acc[4][4];
  #pragma unroll
  for (int i=0;i<4;i++) for (int j=0;j<4;j++) acc[i][j] = (fx4){0.f,0.f,0.f,0.f};
  run_gemm(
    [&](int mi,int ks)->bf16x8{ return *(const bf16x8*)(A + swz(wm*64+mi*16+lr, (ks*32+lk)*2)); },
    [&](int ni,int ks)->bf16x8{ return *(const bf16x8*)(in_w_bf + (size_t)(wn*64+ni*16+lr)*128 + ks*32+lk); },
    acc);
  __syncthreads();   // done reading A; gate waves will overwrite it
  if (wn < 2){
    // carrier: n in [0,128): store bf16 NCHW, 4 consecutive w per 8B store
    #pragma unroll
    for (int mi=0;mi<4;mi++)
      #pragma unroll
      for (int ni=0;ni<4;ni++){
        int n = wn*64 + ni*16 + lr;
        int w0 = wm*64 + mi*16 + ld4;
        float bias = in_b[n];
        ushort4 v;
        v.x=f2bf(acc[mi][ni][0]+bias); v.y=f2bf(acc[mi][ni][1]+bias);
        v.z=f2bf(acc[mi][ni][2]+bias); v.w=f2bf(acc[mi][ni][3]+bias);
        *(ushort4*)(carrier + (size_t)(b*128+n)*16384 + h*128 + w0) = v;
      }
  } else {
    // gate: n in [128,256): silu, write transposed [w][c] into A
    #pragma unroll
    for (int mi=0;mi<4;mi++)
      #pragma unroll
      for (int ni=0;ni<4;ni++){
        int n = wn*64 + ni*16 + lr;     // 128..255
        int c = n - 128;
        int w0 = wm*64 + mi*16 + ld4;
        float bias = in_b[n];
        #pragma unroll
        for (int r=0;r<4;r++){
          float v = acc[mi][ni][r] + bias;
          float s = v / (1.0f + __expf(-v));
          *(unsigned short*)(A + swz(w0+r, c*2)) = f2bf(s);
        }
      }
  }
  __syncthreads();
  // copy gate LDS [w][c] -> global BHWC bf16, coalesced
  {
    unsigned short* gout = gate + (size_t)blk*16384;   // [w][c]
    int w = t >> 2, cq = (t & 3) * 32;
    #pragma unroll
    for (int i=0;i<4;i++){
      int c0 = cq + i*8;
      int4 v = *(const int4*)(A + swz(w, c0*2));
      *(int4*)(gout + w*128 + c0) = v;
    }
  }
}

// ---------------- fused wave kernel: 4 chained MFMA GEMM phases, TWO slices per block ----
// s0 = blk (b in 0..3), s1 = blk+512 (b in 4..7); same c -> shared modT & basis operands.
__global__ __launch_bounds__(256) void wave_kernel(
  const unsigned short* __restrict__ carrier,
  const unsigned short* __restrict__ basis,    // [f][pos] bf16
  const unsigned short* __restrict__ basisT,   // [pos][f] bf16
  const float* __restrict__ modT,              // [c][w-freq][h-freq] fp32
  unsigned short* __restrict__ fused)
{
  __shared__ char U0[32768];
  __shared__ char U1[32768];
  int blk = blockIdx.x;          // 0..511
  int c = blk & 127;
  const unsigned short* X0 = carrier + (size_t)blk*16384;
  const unsigned short* X1 = carrier + (size_t)(blk+512)*16384;
  unsigned short* F0 = fused + (size_t)blk*16384;
  unsigned short* F1 = fused + (size_t)(blk+512)*16384;
  int t = threadIdx.x;
  int l = t & 63, wid = t >> 6;
  int wm = wid >> 1, wn = wid & 1;
  int lr = l & 15, lk = (l>>4)*8, ld4 = (l>>4)*4;
  fx4 acc0[4][4], acc1[4][4];

  #define ZACC { _Pragma("unroll") for (int i=0;i<4;i++) _Pragma("unroll") for (int j=0;j<4;j++){ acc0[i][j]=(fx4){0.f,0.f,0.f,0.f}; acc1[i][j]=(fx4){0.f,0.f,0.f,0.f}; } }
  #define TSTORE(BUF0, BUF1) { \
    _Pragma("unroll") for (int mi=0;mi<4;mi++) \
      _Pragma("unroll") for (int ni=0;ni<4;ni++){ \
        int rr = wn*64 + ni*16 + lr, cc = wm*64 + mi*16 + ld4; \
        bf16x4 v0, v1; \
        v0[0]=(__bf16)acc0[mi][ni][0]; v0[1]=(__bf16)acc0[mi][ni][1]; \
        v0[2]=(__bf16)acc0[mi][ni][2]; v0[3]=(__bf16)acc0[mi][ni][3]; \
        v1[0]=(__bf16)acc1[mi][ni][0]; v1[1]=(__bf16)acc1[mi][ni][1]; \
        v1[2]=(__bf16)acc1[mi][ni][2]; v1[3]=(__bf16)acc1[mi][ni][3]; \
        *(bf16x4*)(BUF0 + swz(rr, cc*2)) = v0; \
        *(bf16x4*)(BUF1 + swz(rr, cc*2)) = v1; \
      } }

  // G1: D1[h][m] = X @ Bw^T  (A0=X0,A1=X1 rows h; B=basis rows m shared; k=w)
  ZACC;
  run_pair_sharedB(
    [&](int mi,int ks)->bf16x8{ return *(const bf16x8*)(X0 + (size_t)(wm*64+mi*16+lr)*128 + ks*32+lk); },
    [&](int mi,int ks)->bf16x8{ return *(const bf16x8*)(X1 + (size_t)(wm*64+mi*16+lr)*128 + ks*32+lk); },
    [&](int ni,int ks)->bf16x8{ return *(const bf16x8*)(basis + (size_t)(wn*64+ni*16+lr)*128 + ks*32+lk); },
    acc0, acc1);
  TSTORE(U0, U1);                // U = D1^T : [m][h]
  __syncthreads();               // bar 1: U ready

  // G2: D2[n][m] = Bh @ U^T  (A=basis rows n shared; B0=U0,B1=U1 rows m; k=h), then modulate
  ZACC;
  run_pair_sharedA(
    [&](int mi,int ks)->bf16x8{ return *(const bf16x8*)(basis + (size_t)(wm*64+mi*16+lr)*128 + ks*32+lk); },
    [&](int ni,int ks)->bf16x8{ return *(const bf16x8*)(U0 + swz(wn*64+ni*16+lr, (ks*32+lk)*2)); },
    [&](int ni,int ks)->bf16x8{ return *(const bf16x8*)(U1 + swz(wn*64+ni*16+lr, (ks*32+lk)*2)); },
    acc0, acc1);
  {
    const float* Mc = modT + (size_t)c*16384;
    #pragma unroll
    for (int mi=0;mi<4;mi++)
      #pragma unroll
      for (int ni=0;ni<4;ni++){
        int n0 = wm*64 + mi*16 + ld4, m = wn*64 + ni*16 + lr;
        fx4 mv = *(const fx4*)(Mc + (size_t)m*128 + n0);
        acc0[mi][ni] *= mv;
        acc1[mi][ni] *= mv;
      }
  }
  __syncthreads();               // bar 2: all reads of U done
  TSTORE(U0, U1);                // U = D2^T : [m][n]
  __syncthreads();               // bar 3: U ready

  // G3: D3[m][h] = U @ Bh  (A0=U0,A1=U1 rows m; B=basisT rows h shared; k=n)
  ZACC;
  run_pair_sharedB(
    [&](int mi,int ks)->bf16x8{ return *(const bf16x8*)(U0 + swz(wm*64+mi*16+lr, (ks*32+lk)*2)); },
    [&](int mi,int ks)->bf16x8{ return *(const bf16x8*)(U1 + swz(wm*64+mi*16+lr, (ks*32+lk)*2)); },
    [&](int ni,int ks)->bf16x8{ return *(const bf16x8*)(basisT + (size_t)(wn*64+ni*16+lr)*128 + ks*32+lk); },
    acc0, acc1);
  __syncthreads();               // bar 4: all reads of U done
  TSTORE(U0, U1);                // U = D3^T : [h][m]
  __syncthreads();               // bar 5: U ready

  // G4: D4[w][h] = BwT @ U^T  (A=basisT rows w shared; B0=U0,B1=U1 rows h; k=m)
  ZACC;
  run_pair_sharedA(
    [&](int mi,int ks)->bf16x8{ return *(const bf16x8*)(basisT + (size_t)(wm*64+mi*16+lr)*128 + ks*32+lk); },
    [&](int ni,int ks)->bf16x8{ return *(const bf16x8*)(U0 + swz(wn*64+ni*16+lr, (ks*32+lk)*2)); },
    [&](int ni,int ks)->bf16x8{ return *(const bf16x8*)(U1 + swz(wn*64+ni*16+lr, (ks*32+lk)*2)); },
    acc0, acc1);
  // store fused[h][w] bf16: D4[row=w][col=h]
  #pragma unroll
  for (int mi=0;mi<4;mi++)
    #pragma unroll
    for (int ni=0;ni<4;ni++){
      int hh = wn*64 + ni*16 + lr, w0 = wm*64 + mi*16 + ld4;
      bf16x4 v0, v1;
      v0[0]=(__bf16)acc0[mi][ni][0]; v0[1]=(__bf16)acc0[mi][ni][1];
      v0[2]=(__bf16)acc0[mi][ni][2]; v0[3]=(__bf16)acc0[mi][ni][3];
      v1[0]=(__bf16)acc1[mi][ni][0]; v1[1]=(__bf16)acc1[mi][ni][1];
      v1[2]=(__bf16)acc1[mi][ni][2]; v1[3]=(__bf16)acc1[mi][ni][3];
      *(bf16x4*)(F0 + hh*128 + w0) = v0;
      *(bf16x4*)(F1 + hh*128 + w0) = v1;
    }
  #undef ZACC
  #undef TSTORE
}

// ---------------- final: LN * silu(gate) @ out_w^T + b -> out NCHW fp32 ----------------
__global__ __launch_bounds__(256) void final_kernel(
  const unsigned short* __restrict__ fused, const unsigned short* __restrict__ gate,
  const unsigned short* __restrict__ out_w_bf, const float* __restrict__ out_b,
  const float* __restrict__ ln_w, const float* __restrict__ ln_b,
  float* __restrict__ out)
{
  __shared__ char Fl[32768];   // F [c][w] swizzled bf16
  __shared__ char Al[32768];   // act [w][c] swizzled bf16
  __shared__ float red[256], red2[256];
  __shared__ float mu[128], rs[128];
  int blk = blockIdx.x; int b = blk>>7, h = blk&127;
  const unsigned short* Fsrc = fused + (size_t)b*2097152 + h*128;  // + c*16384 + w
  const unsigned short* G = gate + (size_t)blk*16384;              // [w][c]
  int t = threadIdx.x;
  // stage F [c][w]
  {
    int c = t>>1, wq = (t&1)*64;
    #pragma unroll
    for (int i=0;i<8;i++){
      int w0 = wq + i*8;
      int4 v = *(const int4*)(Fsrc + (size_t)c*16384 + w0);
      *(int4*)(Fl + swz(c, w0*2)) = v;
    }
  }
  __syncthreads();
  // LN stats per w (reduce over c)
  {
    int w = t&127, half = t>>7;
    float s=0.f, q=0.f;
    for (int i=0;i<64;i++){
      int c = half*64 + i;
      float f = bf2f(*(const unsigned short*)(Fl + swz(c, w*2)));
      s += f; q = fmaf(f,f,q);
    }
    red[t]=s; red2[t]=q;
  }
  __syncthreads();
  if (t < 128){
    float ss = red[t]+red[t+128], qq = red2[t]+red2[t+128];
    float m = ss*(1.f/128.f);
    float var = qq*(1.f/128.f) - m*m;
    mu[t]=m; rs[t]=rsqrtf(var+1e-5f);
  }
  __syncthreads();
  // act[w][c] = LN(F)*silu_gate
  {
    int w = t>>1, cq = (t&1)*64;
    float m_ = mu[w], r_ = rs[w];
    #pragma unroll
    for (int i=0;i<8;i++){
      int c0 = cq + i*8;
      ushort4 g0 = *(const ushort4*)(G + (size_t)w*128 + c0);
      ushort4 g1 = *(const ushort4*)(G + (size_t)w*128 + c0 + 4);
      unsigned short ov[8];
      unsigned short gv[8] = {g0.x,g0.y,g0.z,g0.w,g1.x,g1.y,g1.z,g1.w};
      #pragma unroll
      for (int j=0;j<8;j++){
        int cc = c0+j;
        float f = bf2f(*(const unsigned short*)(Fl + swz(cc, w*2)));
        float a = fmaf((f-m_)*r_, ln_w[cc], ln_b[cc]) * bf2f(gv[j]);
        ov[j] = f2bf(a);
      }
      *(int4*)(Al + swz(w, c0*2)) = *(const int4*)ov;
    }
  }
  __syncthreads();
  // MFMA: D[w][j] = act @ out_w^T
  int l = t & 63, wid = t >> 6;
  int wm = wid >> 1, wn = wid & 1;
  int lr = l & 15, lk = (l>>4)*8, ld4 = (l>>4)*4;
  fx4 acc[4][4];
  #pragma unroll
  for (int i=0;i<4;i++) for (int j=0;j<4;j++) acc[i][j] = (fx4){0.f,0.f,0.f,0.f};
  run_gemm(
    [&](int mi,int ks)->bf16x8{ return *(const bf16x8*)(Al + swz(wm*64+mi*16+lr, (ks*32+lk)*2)); },
    [&](int ni,int ks)->bf16x8{ return *(const bf16x8*)(out_w_bf + (size_t)(wn*64+ni*16+lr)*128 + ks*32+lk); },
    acc);
  #pragma unroll
  for (int mi=0;mi<4;mi++)
    #pragma unroll
    for (int ni=0;ni<4;ni++){
      int j = wn*64 + ni*16 + lr, w0 = wm*64 + mi*16 + ld4;
      float bj = out_b[j];
      fx4 o = acc[mi][ni];
      o[0]+=bj; o[1]+=bj; o[2]+=bj; o[3]+=bj;
      *(fx4*)(out + ((size_t)(b*128 + j)*128 + h)*128 + w0) = o;
    }
}

extern "C" void kernel_launch(void* const* d_in, const int* in_sizes, int n_in,
                              void* d_out, int out_size, void* d_ws, size_t ws_size,
                              hipStream_t stream)
{
  const float* x      = (const float*)d_in[0];
  const float* dw_w   = (const float*)d_in[1];
  const float* dw_b   = (const float*)d_in[2];
  const float* in_w   = (const float*)d_in[3];
  const float* in_b   = (const float*)d_in[4];
  const float* out_w  = (const float*)d_in[5];
  const float* out_b  = (const float*)d_in[6];
  const float* ln_w   = (const float*)d_in[7];
  const float* ln_b   = (const float*)d_in[8];
  const float* ph_w   = (const float*)d_in[9];
  const float* ph_b   = (const float*)d_in[10];
  const float* wsp    = (const float*)d_in[11];
  const float* dmp    = (const float*)d_in[12];
  const float* fe     = (const float*)d_in[13];
  float* outp = (float*)d_out;

  float* modT  = (float*)d_ws;                 // 2,097,152 f32, [c][w-freq][h-freq]
  float* projT = modT + 2097152;               // 2,097,152 f32
  unsigned short* feb      = (unsigned short*)(projT + 2097152);  // 2,097,152 bf16
  unsigned short* conv     = feb     + 2097152;
  unsigned short* carrier  = conv    + 16777216;
  unsigned short* gate     = carrier + 16777216;
  unsigned short* fusedb   = gate    + 16777216;
  unsigned short* basis_bf = fusedb  + 16777216;
  unsigned short* basisT_bf= basis_bf + 16384;
  unsigned short* in_w_bf  = basisT_bf + 16384;
  unsigned short* out_w_bf = in_w_bf + 32768;
  unsigned short* ph_w_bf  = out_w_bf + 16384;

  prep_kernel<<<128,128,0,stream>>>(in_w, ph_w, out_w, basis_bf, basisT_bf, ph_w_bf, in_w_bf, out_w_bf);
  castfe_kernel<<<1024,256,0,stream>>>(fe, feb);
  projk_kernel<<<128,256,0,stream>>>(feb, ph_w_bf, projT);
  modfin_kernel<<<2048,256,0,stream>>>(projT, ph_b, wsp, dmp, modT);
  dwconv_kernel<<<4096,256,0,stream>>>(x, dw_w, dw_b, conv);
  inproj_kernel<<<1024,512,0,stream>>>(conv, in_w_bf, in_b, carrier, gate);
  wave_kernel<<<512,256,0,stream>>>(carrier, basis_bf, basisT_bf, modT, fusedb);
  final_kernel<<<1024,256,0,stream>>>(fusedb, gate, out_w_bf, out_b, ln_w, ln_b, outp);
}

// Round 12
// 169.382 us; speedup vs baseline: 1.1861x; 1.0140x over previous
//
#include <hip/hip_runtime.h>
#include <math.h>

#ifndef M_PI
#define M_PI 3.14159265358979323846
#endif

typedef float fx4 __attribute__((ext_vector_type(4)));
typedef __bf16 bf16x8 __attribute__((ext_vector_type(8)));
typedef __bf16 bf16x4 __attribute__((ext_vector_type(4)));

__device__ __forceinline__ unsigned short f2bf(float f){
  union { float f; unsigned u; } v; v.f = f;
  unsigned r = v.u + 0x7FFFu + ((v.u >> 16) & 1u);
  return (unsigned short)(r >> 16);
}
__device__ __forceinline__ float bf2f(unsigned short u){
  union { unsigned u; float f; } v; v.u = ((unsigned)u) << 16;
  return v.f;
}
// swizzled byte offset within a [row][128] bf16 tile (256 B rows)
__device__ __forceinline__ int swz(int row, int colbyte){
  return row*256 + (colbyte ^ ((row & 7) << 4));
}

// Double-buffered 128-deep (per-wave 64x64) MFMA GEMM core.
template<typename FA, typename FB>
__device__ __forceinline__ void run_gemm(FA la, FB lb, fx4 (&acc)[4][4]){
  bf16x8 a[2][4], b[2][4];
  #pragma unroll
  for (int mi=0;mi<4;mi++){ a[0][mi]=la(mi,0); b[0][mi]=lb(mi,0); }
  #pragma unroll
  for (int ks=0; ks<4; ks++){
    int cur = ks&1, nxt = cur^1;
    if (ks<3){
      #pragma unroll
      for (int mi=0;mi<4;mi++){ a[nxt][mi]=la(mi,ks+1); b[nxt][mi]=lb(mi,ks+1); }
    }
    #pragma unroll
    for (int mi=0;mi<4;mi++)
      #pragma unroll
      for (int ni=0;ni<4;ni++)
        acc[mi][ni] = __builtin_amdgcn_mfma_f32_16x16x32_bf16(a[cur][mi], b[cur][ni], acc[mi][ni], 0, 0, 0);
  }
}

// Two-tile pair, shared B operand: acc0 = A0*B, acc1 = A1*B.
template<typename FA0, typename FA1, typename FB>
__device__ __forceinline__ void run_pair_sharedB(FA0 la0, FA1 la1, FB lb,
                                                 fx4 (&acc0)[4][4], fx4 (&acc1)[4][4]){
  bf16x8 a0[2][4], a1[2][4], b[2][4];
  #pragma unroll
  for (int mi=0;mi<4;mi++){ a0[0][mi]=la0(mi,0); a1[0][mi]=la1(mi,0); b[0][mi]=lb(mi,0); }
  #pragma unroll
  for (int ks=0; ks<4; ks++){
    int cur = ks&1, nxt = cur^1;
    if (ks<3){
      #pragma unroll
      for (int mi=0;mi<4;mi++){ a0[nxt][mi]=la0(mi,ks+1); a1[nxt][mi]=la1(mi,ks+1); b[nxt][mi]=lb(mi,ks+1); }
    }
    #pragma unroll
    for (int mi=0;mi<4;mi++)
      #pragma unroll
      for (int ni=0;ni<4;ni++){
        acc0[mi][ni] = __builtin_amdgcn_mfma_f32_16x16x32_bf16(a0[cur][mi], b[cur][ni], acc0[mi][ni], 0, 0, 0);
        acc1[mi][ni] = __builtin_amdgcn_mfma_f32_16x16x32_bf16(a1[cur][mi], b[cur][ni], acc1[mi][ni], 0, 0, 0);
      }
  }
}

// Two-tile pair, shared A operand: acc0 = A*B0, acc1 = A*B1.
template<typename FA, typename FB0, typename FB1>
__device__ __forceinline__ void run_pair_sharedA(FA la, FB0 lb0, FB1 lb1,
                                                 fx4 (&acc0)[4][4], fx4 (&acc1)[4][4]){
  bf16x8 a[2][4], b0[2][4], b1[2][4];
  #pragma unroll
  for (int mi=0;mi<4;mi++){ a[0][mi]=la(mi,0); b0[0][mi]=lb0(mi,0); b1[0][mi]=lb1(mi,0); }
  #pragma unroll
  for (int ks=0; ks<4; ks++){
    int cur = ks&1, nxt = cur^1;
    if (ks<3){
      #pragma unroll
      for (int mi=0;mi<4;mi++){ a[nxt][mi]=la(mi,ks+1); b0[nxt][mi]=lb0(mi,ks+1); b1[nxt][mi]=lb1(mi,ks+1); }
    }
    #pragma unroll
    for (int mi=0;mi<4;mi++)
      #pragma unroll
      for (int ni=0;ni<4;ni++){
        acc0[mi][ni] = __builtin_amdgcn_mfma_f32_16x16x32_bf16(a[cur][mi], b0[cur][ni], acc0[mi][ni], 0, 0, 0);
        acc1[mi][ni] = __builtin_amdgcn_mfma_f32_16x16x32_bf16(a[cur][mi], b1[cur][ni], acc1[mi][ni], 0, 0, 0);
      }
  }
}

// ================= K1: prep || castfe || dwconv (independent, blockIdx-partitioned) =====
__global__ __launch_bounds__(256) void k1_prep_cast_conv(
    const float* __restrict__ in_w, const float* __restrict__ ph_w,
    const float* __restrict__ out_w, const float* __restrict__ fe,
    const float* __restrict__ x, const float* __restrict__ dw_w,
    const float* __restrict__ dw_b,
    unsigned short* __restrict__ basis_bf, unsigned short* __restrict__ basisT_bf,
    unsigned short* __restrict__ ph_w_bf, unsigned short* __restrict__ in_w_bf,
    unsigned short* __restrict__ out_w_bf, unsigned short* __restrict__ feb,
    unsigned short* __restrict__ conv)
{
  int blk = blockIdx.x;
  int t = threadIdx.x;
  if (blk < 128){
    // ---- prep ----
    if (t >= 128) return;
    int n = blk, h = t;
    double arg = (double)(n*(2*h+1)) * (M_PI/256.0);
    double v = cos(arg) * 0.125;
    if (n==0) v *= 0.7071067811865476;
    unsigned short bv = f2bf((float)v);
    basis_bf[n*128+h]  = bv;
    basisT_bf[h*128+n] = bv;
    ph_w_bf[n*128+h]  = f2bf(ph_w[n*128+h]);
    in_w_bf[n*128+h]        = f2bf(in_w[n*128+h]);
    in_w_bf[(n+128)*128+h]  = f2bf(in_w[(n+128)*128+h]);
    out_w_bf[n*128+h]       = f2bf(out_w[n*128+h]);
    return;
  }
  if (blk < 1152){
    // ---- castfe ----
    int idx = (blk-128)*256 + t;
    const float* s = fe + (size_t)idx*8;
    float4 f0 = *(const float4*)s;
    float4 f1 = *(const float4*)(s+4);
    unsigned short o[8];
    o[0]=f2bf(f0.x); o[1]=f2bf(f0.y); o[2]=f2bf(f0.z); o[3]=f2bf(f0.w);
    o[4]=f2bf(f1.x); o[5]=f2bf(f1.y); o[6]=f2bf(f1.z); o[7]=f2bf(f1.w);
    *(int4*)(feb + (size_t)idx*8) = *(const int4*)o;
    return;
  }
  // ---- dwconv ----
  {
    int bb = blk - 1152;           // plane*4 + band
    int plane = bb >> 2, band = bb & 3;
    int c = plane & 127;
    const float* xp = x + (size_t)plane*16384;
    unsigned short* op = conv + (size_t)plane*16384;
    const float* kw = dw_w + c*9;
    float k0=kw[0],k1=kw[1],k2=kw[2],k3=kw[3],k4=kw[4],k5=kw[5],k6=kw[6],k7=kw[7],k8=kw[8];
    float bias = dw_b[c];
    int q = t & 31;
    int w0 = q*4;
    int rg = t >> 5;
    int h0 = band*32 + rg*4;
    bool le = (q==0), re = (q==31);
    float4 fA, fB, fC; float lA,rA,lB,rB,lC,rC;
    #define LOADROW(hh, f, l, r) { \
      int hc = (hh)<0 ? 0 : ((hh)>127 ? 127 : (hh)); \
      f = *(const float4*)(xp + hc*128 + w0); \
      float lu = __shfl_up(f.w, 1, 32); \
      float rd = __shfl_down(f.x, 1, 32); \
      l = le ? 0.f : lu; \
      r = re ? 0.f : rd; \
      if ((hh)<0 || (hh)>127){ f = make_float4(0.f,0.f,0.f,0.f); l=0.f; r=0.f; } \
    }
    LOADROW(h0-1, fA,lA,rA);
    LOADROW(h0,   fB,lB,rB);
    #pragma unroll
    for (int i=0;i<4;i++){
      LOADROW(h0+1+i, fC,lC,rC);
      float4 o;
      o.x = bias; o.y = bias; o.z = bias; o.w = bias;
      o.x = fmaf(k0,lA,  fmaf(k1,fA.x, fmaf(k2,fA.y, o.x)));
      o.y = fmaf(k0,fA.x,fmaf(k1,fA.y, fmaf(k2,fA.z, o.y)));
      o.z = fmaf(k0,fA.y,fmaf(k1,fA.z, fmaf(k2,fA.w, o.z)));
      o.w = fmaf(k0,fA.z,fmaf(k1,fA.w, fmaf(k2,rA,   o.w)));
      o.x = fmaf(k3,lB,  fmaf(k4,fB.x, fmaf(k5,fB.y, o.x)));
      o.y = fmaf(k3,fB.x,fmaf(k4,fB.y, fmaf(k5,fB.z, o.y)));
      o.z = fmaf(k3,fB.y,fmaf(k4,fB.z, fmaf(k5,fB.w, o.z)));
      o.w = fmaf(k3,fB.z,fmaf(k4,fB.w, fmaf(k5,rB,   o.w)));
      o.x = fmaf(k6,lC,  fmaf(k7,fC.x, fmaf(k8,fC.y, o.x)));
      o.y = fmaf(k6,fC.x,fmaf(k7,fC.y, fmaf(k8,fC.z, o.y)));
      o.z = fmaf(k6,fC.y,fmaf(k7,fC.z, fmaf(k8,fC.w, o.z)));
      o.w = fmaf(k6,fC.z,fmaf(k7,fC.w, fmaf(k8,rC,   o.w)));
      bf16x4 v;
      v[0]=(__bf16)o.x; v[1]=(__bf16)o.y; v[2]=(__bf16)o.z; v[3]=(__bf16)o.w;
      *(bf16x4*)(op + (size_t)(h0+i)*128 + w0) = v;
      fA=fB; lA=lB; rA=rB;
      fB=fC; lB=lC; rB=rC;
    }
    #undef LOADROW
  }
}

// ================= K2: inproj-pair (blocks 0..511) || projk (blocks 512..639) ===========
// inproj-pair: two adjacent h-pixels per block, shared in_w B operand.
__global__ __launch_bounds__(512) void k2_inproj_projk(
  const unsigned short* __restrict__ conv, const unsigned short* __restrict__ in_w_bf,
  const float* __restrict__ in_b, unsigned short* __restrict__ carrier,
  unsigned short* __restrict__ gate,
  const unsigned short* __restrict__ feb, const unsigned short* __restrict__ ph_w_bf,
  float* __restrict__ projT)
{
  int blk = blockIdx.x;
  int t = threadIdx.x;
  if (blk >= 512){
    // ---- projk (256 active threads) ----
    if (t >= 256) return;
    int r0 = (blk - 512) * 128;
    int l = t & 63, wid = t >> 6;
    int wm = wid >> 1, wn = wid & 1;
    int lr = l & 15, lk = (l>>4)*8, ld4 = (l>>4)*4;
    fx4 acc[4][4];
    #pragma unroll
    for (int i=0;i<4;i++) for (int j=0;j<4;j++) acc[i][j] = (fx4){0.f,0.f,0.f,0.f};
    run_gemm(
      [&](int mi,int ks)->bf16x8{ return *(const bf16x8*)(feb + (size_t)(r0 + wm*64+mi*16+lr)*128 + ks*32+lk); },
      [&](int ni,int ks)->bf16x8{ return *(const bf16x8*)(ph_w_bf + (size_t)(wn*64+ni*16+lr)*128 + ks*32+lk); },
      acc);
    #pragma unroll
    for (int mi=0;mi<4;mi++)
      #pragma unroll
      for (int ni=0;ni<4;ni++){
        int c = wn*64 + ni*16 + lr;
        int r = r0 + wm*64 + mi*16 + ld4;
        *(fx4*)(projT + (size_t)c*16384 + r) = acc[mi][ni];
      }
    return;
  }
  // ---- inproj-pair ----
  __shared__ char A0[32768];   // pixel h0: [w][c] swizzled; reused for gate
  __shared__ char A1[32768];   // pixel h1
  int b = blk >> 6, hp = blk & 63;
  int h0 = hp*2, h1 = h0+1;
  const unsigned short* C0 = conv + (size_t)b*2097152 + h0*128;  // + c*16384 + w
  const unsigned short* C1 = C0 + 128;
  // stage both pixels: gather conv [c][w] columns -> LDS [w][c]
  {
    int wl = t & 63, grp = (t >> 6) & 7;
    int p = 0;
    #pragma unroll
    for (p=0;p<2;p++){
      int w = wl + 64*p;
      #pragma unroll
      for (int q=0;q<4;q++){
        int c0 = (q*8 + grp)*4;
        ushort4 v0, v1;
        v0.x = C0[(size_t)(c0+0)*16384 + w];
        v0.y = C0[(size_t)(c0+1)*16384 + w];
        v0.z = C0[(size_t)(c0+2)*16384 + w];
        v0.w = C0[(size_t)(c0+3)*16384 + w];
        v1.x = C1[(size_t)(c0+0)*16384 + w];
        v1.y = C1[(size_t)(c0+1)*16384 + w];
        v1.z = C1[(size_t)(c0+2)*16384 + w];
        v1.w = C1[(size_t)(c0+3)*16384 + w];
        *(ushort4*)(A0 + swz(w, c0*2)) = v0;
        *(ushort4*)(A1 + swz(w, c0*2)) = v1;
      }
    }
  }
  __syncthreads();
  int l = t & 63, wid = t >> 6;
  int wm = wid >> 2, wn = wid & 3;   // 2 x 4 waves, 64x64 quadrants over M=128,N=256
  int lr = l & 15, lk = (l>>4)*8, ld4 = (l>>4)*4;
  fx4 acc0[4][4], acc1[4][4];
  #pragma unroll
  for (int i=0;i<4;i++) for (int j=0;j<4;j++){ acc0[i][j]=(fx4){0.f,0.f,0.f,0.f}; acc1[i][j]=(fx4){0.f,0.f,0.f,0.f}; }
  run_pair_sharedB(
    [&](int mi,int ks)->bf16x8{ return *(const bf16x8*)(A0 + swz(wm*64+mi*16+lr, (ks*32+lk)*2)); },
    [&](int mi,int ks)->bf16x8{ return *(const bf16x8*)(A1 + swz(wm*64+mi*16+lr, (ks*32+lk)*2)); },
    [&](int ni,int ks)->bf16x8{ return *(const bf16x8*)(in_w_bf + (size_t)(wn*64+ni*16+lr)*128 + ks*32+lk); },
    acc0, acc1);
  __syncthreads();   // all MFMA reads of A0/A1 done; gate waves will overwrite
  if (wn < 2){
    // carrier: n in [0,128): bf16 NCHW stores for both pixels
    #pragma unroll
    for (int mi=0;mi<4;mi++)
      #pragma unroll
      for (int ni=0;ni<4;ni++){
        int n = wn*64 + ni*16 + lr;
        int w0 = wm*64 + mi*16 + ld4;
        float bias = in_b[n];
        unsigned short* base = carrier + (size_t)(b*128+n)*16384 + w0;
        ushort4 v0, v1;
        v0.x=f2bf(acc0[mi][ni][0]+bias); v0.y=f2bf(acc0[mi][ni][1]+bias);
        v0.z=f2bf(acc0[mi][ni][2]+bias); v0.w=f2bf(acc0[mi][ni][3]+bias);
        v1.x=f2bf(acc1[mi][ni][0]+bias); v1.y=f2bf(acc1[mi][ni][1]+bias);
        v1.z=f2bf(acc1[mi][ni][2]+bias); v1.w=f2bf(acc1[mi][ni][3]+bias);
        *(ushort4*)(base + h0*128) = v0;
        *(ushort4*)(base + h1*128) = v1;
      }
  } else {
    // gate: n in [128,256): silu -> LDS [w][c] (A0 for pixel0, A1 for pixel1)
    #pragma unroll
    for (int mi=0;mi<4;mi++)
      #pragma unroll
      for (int ni=0;ni<4;ni++){
        int n = wn*64 + ni*16 + lr;     // 128..255
        int c = n - 128;
        int w0 = wm*64 + mi*16 + ld4;
        float bias = in_b[n];
        #pragma unroll
        for (int r=0;r<4;r++){
          float v0 = acc0[mi][ni][r] + bias;
          float v1 = acc1[mi][ni][r] + bias;
          float s0 = v0 / (1.0f + __expf(-v0));
          float s1 = v1 / (1.0f + __expf(-v1));
          *(unsigned short*)(A0 + swz(w0+r, c*2)) = f2bf(s0);
          *(unsigned short*)(A1 + swz(w0+r, c*2)) = f2bf(s1);
        }
      }
  }
  __syncthreads();
  // copy gate LDS [w][c] -> global BHWC bf16 for both pixels, coalesced
  {
    unsigned short* g0 = gate + ((size_t)(b*128+h0))*16384;   // [w][c]
    unsigned short* g1 = gate + ((size_t)(b*128+h1))*16384;
    int w = t >> 2, cq = (t & 3) * 32;
    #pragma unroll
    for (int i=0;i<4;i++){
      int c0 = cq + i*8;
      int4 v0 = *(const int4*)(A0 + swz(w, c0*2));
      int4 v1 = *(const int4*)(A1 + swz(w, c0*2));
      *(int4*)(g0 + w*128 + c0) = v0;
      *(int4*)(g1 + w*128 + c0) = v1;
    }
  }
}

// ---------------- modfin: factor -> modT[c][q][p]  (q = fe-col = freq-w, p = fe-row = freq-h)
__global__ __launch_bounds__(256) void modfin_kernel(
  const float* __restrict__ projT, const float* __restrict__ ph_b,
  const float* __restrict__ wave_speed, const float* __restrict__ damping,
  float* __restrict__ modT)
{
  int blk = blockIdx.x;
  int c = blk >> 4, qb = blk & 15;
  int t = threadIdx.x;
  int q = qb*8 + (t>>5);
  int p0 = (t & 31)*4;
  float ws0 = wave_speed[0];
  float dmp = damping[0];
  float inv = 1.0f / fmaxf(fabsf(ws0), 1e-6f);
  float dampf = 1.0f + 0.5f*dmp;
  float bc = ph_b[c];
  const float* src = projT + (size_t)c*16384 + q;
  float o[4];
  #pragma unroll
  for (int i=0;i<4;i++){
    float v = src[(size_t)(p0+i)*128] + bc;
    float g = 0.5f*v*(1.0f + erff(v*0.70710678118f));
    float wp = ws0*g;
    o[i] = __cosf(wp) + __sinf(wp)*inv*dampf;
  }
  *(float4*)(modT + ((size_t)c*128 + q)*128 + p0) = make_float4(o[0],o[1],o[2],o[3]);
}

// ---------------- fused wave kernel: 4 chained MFMA GEMM phases, TWO slices per block ----
__global__ __launch_bounds__(256) void wave_kernel(
  const unsigned short* __restrict__ carrier,
  const unsigned short* __restrict__ basis,    // [f][pos] bf16
  const unsigned short* __restrict__ basisT,   // [pos][f] bf16
  const float* __restrict__ modT,              // [c][w-freq][h-freq] fp32
  unsigned short* __restrict__ fused)
{
  __shared__ char U0[32768];
  __shared__ char U1[32768];
  int blk = blockIdx.x;          // 0..511
  int c = blk & 127;
  const unsigned short* X0 = carrier + (size_t)blk*16384;
  const unsigned short* X1 = carrier + (size_t)(blk+512)*16384;
  unsigned short* F0 = fused + (size_t)blk*16384;
  unsigned short* F1 = fused + (size_t)(blk+512)*16384;
  int t = threadIdx.x;
  int l = t & 63, wid = t >> 6;
  int wm = wid >> 1, wn = wid & 1;
  int lr = l & 15, lk = (l>>4)*8, ld4 = (l>>4)*4;
  fx4 acc0[4][4], acc1[4][4];

  #define ZACC { _Pragma("unroll") for (int i=0;i<4;i++) _Pragma("unroll") for (int j=0;j<4;j++){ acc0[i][j]=(fx4){0.f,0.f,0.f,0.f}; acc1[i][j]=(fx4){0.f,0.f,0.f,0.f}; } }
  #define TSTORE(BUF0, BUF1) { \
    _Pragma("unroll") for (int mi=0;mi<4;mi++) \
      _Pragma("unroll") for (int ni=0;ni<4;ni++){ \
        int rr = wn*64 + ni*16 + lr, cc = wm*64 + mi*16 + ld4; \
        bf16x4 v0, v1; \
        v0[0]=(__bf16)acc0[mi][ni][0]; v0[1]=(__bf16)acc0[mi][ni][1]; \
        v0[2]=(__bf16)acc0[mi][ni][2]; v0[3]=(__bf16)acc0[mi][ni][3]; \
        v1[0]=(__bf16)acc1[mi][ni][0]; v1[1]=(__bf16)acc1[mi][ni][1]; \
        v1[2]=(__bf16)acc1[mi][ni][2]; v1[3]=(__bf16)acc1[mi][ni][3]; \
        *(bf16x4*)(BUF0 + swz(rr, cc*2)) = v0; \
        *(bf16x4*)(BUF1 + swz(rr, cc*2)) = v1; \
      } }

  // G1: D1[h][m] = X @ Bw^T
  ZACC;
  run_pair_sharedB(
    [&](int mi,int ks)->bf16x8{ return *(const bf16x8*)(X0 + (size_t)(wm*64+mi*16+lr)*128 + ks*32+lk); },
    [&](int mi,int ks)->bf16x8{ return *(const bf16x8*)(X1 + (size_t)(wm*64+mi*16+lr)*128 + ks*32+lk); },
    [&](int ni,int ks)->bf16x8{ return *(const bf16x8*)(basis + (size_t)(wn*64+ni*16+lr)*128 + ks*32+lk); },
    acc0, acc1);
  TSTORE(U0, U1);                // U = D1^T : [m][h]
  __syncthreads();               // bar 1

  // G2: D2[n][m] = Bh @ U^T, then modulate
  ZACC;
  run_pair_sharedA(
    [&](int mi,int ks)->bf16x8{ return *(const bf16x8*)(basis + (size_t)(wm*64+mi*16+lr)*128 + ks*32+lk); },
    [&](int ni,int ks)->bf16x8{ return *(const bf16x8*)(U0 + swz(wn*64+ni*16+lr, (ks*32+lk)*2)); },
    [&](int ni,int ks)->bf16x8{ return *(const bf16x8*)(U1 + swz(wn*64+ni*16+lr, (ks*32+lk)*2)); },
    acc0, acc1);
  {
    const float* Mc = modT + (size_t)c*16384;
    #pragma unroll
    for (int mi=0;mi<4;mi++)
      #pragma unroll
      for (int ni=0;ni<4;ni++){
        int n0 = wm*64 + mi*16 + ld4, m = wn*64 + ni*16 + lr;
        fx4 mv = *(const fx4*)(Mc + (size_t)m*128 + n0);
        acc0[mi][ni] *= mv;
        acc1[mi][ni] *= mv;
      }
  }
  __syncthreads();               // bar 2
  TSTORE(U0, U1);                // U = D2^T : [m][n]
  __syncthreads();               // bar 3

  // G3: D3[m][h] = U @ Bh
  ZACC;
  run_pair_sharedB(
    [&](int mi,int ks)->bf16x8{ return *(const bf16x8*)(U0 + swz(wm*64+mi*16+lr, (ks*32+lk)*2)); },
    [&](int mi,int ks)->bf16x8{ return *(const bf16x8*)(U1 + swz(wm*64+mi*16+lr, (ks*32+lk)*2)); },
    [&](int ni,int ks)->bf16x8{ return *(const bf16x8*)(basisT + (size_t)(wn*64+ni*16+lr)*128 + ks*32+lk); },
    acc0, acc1);
  __syncthreads();               // bar 4
  TSTORE(U0, U1);                // U = D3^T : [h][m]
  __syncthreads();               // bar 5

  // G4: D4[w][h] = BwT @ U^T
  ZACC;
  run_pair_sharedA(
    [&](int mi,int ks)->bf16x8{ return *(const bf16x8*)(basisT + (size_t)(wm*64+mi*16+lr)*128 + ks*32+lk); },
    [&](int ni,int ks)->bf16x8{ return *(const bf16x8*)(U0 + swz(wn*64+ni*16+lr, (ks*32+lk)*2)); },
    [&](int ni,int ks)->bf16x8{ return *(const bf16x8*)(U1 + swz(wn*64+ni*16+lr, (ks*32+lk)*2)); },
    acc0, acc1);
  #pragma unroll
  for (int mi=0;mi<4;mi++)
    #pragma unroll
    for (int ni=0;ni<4;ni++){
      int hh = wn*64 + ni*16 + lr, w0 = wm*64 + mi*16 + ld4;
      bf16x4 v0, v1;
      v0[0]=(__bf16)acc0[mi][ni][0]; v0[1]=(__bf16)acc0[mi][ni][1];
      v0[2]=(__bf16)acc0[mi][ni][2]; v0[3]=(__bf16)acc0[mi][ni][3];
      v1[0]=(__bf16)acc1[mi][ni][0]; v1[1]=(__bf16)acc1[mi][ni][1];
      v1[2]=(__bf16)acc1[mi][ni][2]; v1[3]=(__bf16)acc1[mi][ni][3];
      *(bf16x4*)(F0 + hh*128 + w0) = v0;
      *(bf16x4*)(F1 + hh*128 + w0) = v1;
    }
  #undef ZACC
  #undef TSTORE
}

// ---------------- final: LN * silu(gate) @ out_w^T + b -> out NCHW fp32 ----------------
__global__ __launch_bounds__(256) void final_kernel(
  const unsigned short* __restrict__ fused, const unsigned short* __restrict__ gate,
  const unsigned short* __restrict__ out_w_bf, const float* __restrict__ out_b,
  const float* __restrict__ ln_w, const float* __restrict__ ln_b,
  float* __restrict__ out)
{
  __shared__ char Fl[32768];   // F [c][w] swizzled bf16
  __shared__ char Al[32768];   // act [w][c] swizzled bf16
  __shared__ float red[256], red2[256];
  __shared__ float mu[128], rs[128];
  int blk = blockIdx.x; int b = blk>>7, h = blk&127;
  const unsigned short* Fsrc = fused + (size_t)b*2097152 + h*128;  // + c*16384 + w
  const unsigned short* G = gate + (size_t)blk*16384;              // [w][c]
  int t = threadIdx.x;
  // stage F [c][w]
  {
    int c = t>>1, wq = (t&1)*64;
    #pragma unroll
    for (int i=0;i<8;i++){
      int w0 = wq + i*8;
      int4 v = *(const int4*)(Fsrc + (size_t)c*16384 + w0);
      *(int4*)(Fl + swz(c, w0*2)) = v;
    }
  }
  __syncthreads();
  // LN stats per w (reduce over c)
  {
    int w = t&127, half = t>>7;
    float s=0.f, q=0.f;
    for (int i=0;i<64;i++){
      int c = half*64 + i;
      float f = bf2f(*(const unsigned short*)(Fl + swz(c, w*2)));
      s += f; q = fmaf(f,f,q);
    }
    red[t]=s; red2[t]=q;
  }
  __syncthreads();
  if (t < 128){
    float ss = red[t]+red[t+128], qq = red2[t]+red2[t+128];
    float m = ss*(1.f/128.f);
    float var = qq*(1.f/128.f) - m*m;
    mu[t]=m; rs[t]=rsqrtf(var+1e-5f);
  }
  __syncthreads();
  // act[w][c] = LN(F)*silu_gate
  {
    int w = t>>1, cq = (t&1)*64;
    float m_ = mu[w], r_ = rs[w];
    #pragma unroll
    for (int i=0;i<8;i++){
      int c0 = cq + i*8;
      ushort4 g0 = *(const ushort4*)(G + (size_t)w*128 + c0);
      ushort4 g1 = *(const ushort4*)(G + (size_t)w*128 + c0 + 4);
      unsigned short ov[8];
      unsigned short gv[8] = {g0.x,g0.y,g0.z,g0.w,g1.x,g1.y,g1.z,g1.w};
      #pragma unroll
      for (int j=0;j<8;j++){
        int cc = c0+j;
        float f = bf2f(*(const unsigned short*)(Fl + swz(cc, w*2)));
        float a = fmaf((f-m_)*r_, ln_w[cc], ln_b[cc]) * bf2f(gv[j]);
        ov[j] = f2bf(a);
      }
      *(int4*)(Al + swz(w, c0*2)) = *(const int4*)ov;
    }
  }
  __syncthreads();
  // MFMA: D[w][j] = act @ out_w^T
  int l = t & 63, wid = t >> 6;
  int wm = wid >> 1, wn = wid & 1;
  int lr = l & 15, lk = (l>>4)*8, ld4 = (l>>4)*4;
  fx4 acc[4][4];
  #pragma unroll
  for (int i=0;i<4;i++) for (int j=0;j<4;j++) acc[i][j] = (fx4){0.f,0.f,0.f,0.f};
  run_gemm(
    [&](int mi,int ks)->bf16x8{ return *(const bf16x8*)(Al + swz(wm*64+mi*16+lr, (ks*32+lk)*2)); },
    [&](int ni,int ks)->bf16x8{ return *(const bf16x8*)(out_w_bf + (size_t)(wn*64+ni*16+lr)*128 + ks*32+lk); },
    acc);
  #pragma unroll
  for (int mi=0;mi<4;mi++)
    #pragma unroll
    for (int ni=0;ni<4;ni++){
      int j = wn*64 + ni*16 + lr, w0 = wm*64 + mi*16 + ld4;
      float bj = out_b[j];
      fx4 o = acc[mi][ni];
      o[0]+=bj; o[1]+=bj; o[2]+=bj; o[3]+=bj;
      *(fx4*)(out + ((size_t)(b*128 + j)*128 + h)*128 + w0) = o;
    }
}

extern "C" void kernel_launch(void* const* d_in, const int* in_sizes, int n_in,
                              void* d_out, int out_size, void* d_ws, size_t ws_size,
                              hipStream_t stream)
{
  const float* x      = (const float*)d_in[0];
  const float* dw_w   = (const float*)d_in[1];
  const float* dw_b   = (const float*)d_in[2];
  const float* in_w   = (const float*)d_in[3];
  const float* in_b   = (const float*)d_in[4];
  const float* out_w  = (const float*)d_in[5];
  const float* out_b  = (const float*)d_in[6];
  const float* ln_w   = (const float*)d_in[7];
  const float* ln_b   = (const float*)d_in[8];
  const float* ph_w   = (const float*)d_in[9];
  const float* ph_b   = (const float*)d_in[10];
  const float* wsp    = (const float*)d_in[11];
  const float* dmp    = (const float*)d_in[12];
  const float* fe     = (const float*)d_in[13];
  float* outp = (float*)d_out;

  float* modT  = (float*)d_ws;                 // 2,097,152 f32, [c][w-freq][h-freq]
  float* projT = modT + 2097152;               // 2,097,152 f32
  unsigned short* feb      = (unsigned short*)(projT + 2097152);  // 2,097,152 bf16
  unsigned short* conv     = feb     + 2097152;
  unsigned short* carrier  = conv    + 16777216;
  unsigned short* gate     = carrier + 16777216;
  unsigned short* fusedb   = gate    + 16777216;
  unsigned short* basis_bf = fusedb  + 16777216;
  unsigned short* basisT_bf= basis_bf + 16384;
  unsigned short* in_w_bf  = basisT_bf + 16384;
  unsigned short* out_w_bf = in_w_bf + 32768;
  unsigned short* ph_w_bf  = out_w_bf + 16384;

  k1_prep_cast_conv<<<5248,256,0,stream>>>(in_w, ph_w, out_w, fe, x, dw_w, dw_b,
      basis_bf, basisT_bf, ph_w_bf, in_w_bf, out_w_bf, feb, conv);
  k2_inproj_projk<<<640,512,0,stream>>>(conv, in_w_bf, in_b, carrier, gate,
      feb, ph_w_bf, projT);
  modfin_kernel<<<2048,256,0,stream>>>(projT, ph_b, wsp, dmp, modT);
  wave_kernel<<<512,256,0,stream>>>(carrier, basis_bf, basisT_bf, modT, fusedb);
  final_kernel<<<1024,256,0,stream>>>(fusedb, gate, out_w_bf, out_b, ln_w, ln_b, outp);
}

// Round 13
// 156.366 us; speedup vs baseline: 1.2848x; 1.0832x over previous
//
#include <hip/hip_runtime.h>
#include <math.h>

#ifndef M_PI
#define M_PI 3.14159265358979323846
#endif

typedef float fx4 __attribute__((ext_vector_type(4)));
typedef __bf16 bf16x8 __attribute__((ext_vector_type(8)));
typedef __bf16 bf16x4 __attribute__((ext_vector_type(4)));

__device__ __forceinline__ unsigned short f2bf(float f){
  union { float f; unsigned u; } v; v.f = f;
  unsigned r = v.u + 0x7FFFu + ((v.u >> 16) & 1u);
  return (unsigned short)(r >> 16);
}
__device__ __forceinline__ float bf2f(unsigned short u){
  union { unsigned u; float f; } v; v.u = ((unsigned)u) << 16;
  return v.f;
}
// swizzled byte offset within a [row][128] bf16 tile (256 B rows)
__device__ __forceinline__ int swz(int row, int colbyte){
  return row*256 + (colbyte ^ ((row & 7) << 4));
}

// Double-buffered 128-deep (per-wave 64x64) MFMA GEMM core.
template<typename FA, typename FB>
__device__ __forceinline__ void run_gemm(FA la, FB lb, fx4 (&acc)[4][4]){
  bf16x8 a[2][4], b[2][4];
  #pragma unroll
  for (int mi=0;mi<4;mi++){ a[0][mi]=la(mi,0); b[0][mi]=lb(mi,0); }
  #pragma unroll
  for (int ks=0; ks<4; ks++){
    int cur = ks&1, nxt = cur^1;
    if (ks<3){
      #pragma unroll
      for (int mi=0;mi<4;mi++){ a[nxt][mi]=la(mi,ks+1); b[nxt][mi]=lb(mi,ks+1); }
    }
    #pragma unroll
    for (int mi=0;mi<4;mi++)
      #pragma unroll
      for (int ni=0;ni<4;ni++)
        acc[mi][ni] = __builtin_amdgcn_mfma_f32_16x16x32_bf16(a[cur][mi], b[cur][ni], acc[mi][ni], 0, 0, 0);
  }
}

// Two-tile pair, shared B operand: acc0 = A0*B, acc1 = A1*B.
template<typename FA0, typename FA1, typename FB>
__device__ __forceinline__ void run_pair_sharedB(FA0 la0, FA1 la1, FB lb,
                                                 fx4 (&acc0)[4][4], fx4 (&acc1)[4][4]){
  bf16x8 a0[2][4], a1[2][4], b[2][4];
  #pragma unroll
  for (int mi=0;mi<4;mi++){ a0[0][mi]=la0(mi,0); a1[0][mi]=la1(mi,0); b[0][mi]=lb(mi,0); }
  #pragma unroll
  for (int ks=0; ks<4; ks++){
    int cur = ks&1, nxt = cur^1;
    if (ks<3){
      #pragma unroll
      for (int mi=0;mi<4;mi++){ a0[nxt][mi]=la0(mi,ks+1); a1[nxt][mi]=la1(mi,ks+1); b[nxt][mi]=lb(mi,ks+1); }
    }
    #pragma unroll
    for (int mi=0;mi<4;mi++)
      #pragma unroll
      for (int ni=0;ni<4;ni++){
        acc0[mi][ni] = __builtin_amdgcn_mfma_f32_16x16x32_bf16(a0[cur][mi], b[cur][ni], acc0[mi][ni], 0, 0, 0);
        acc1[mi][ni] = __builtin_amdgcn_mfma_f32_16x16x32_bf16(a1[cur][mi], b[cur][ni], acc1[mi][ni], 0, 0, 0);
      }
  }
}

// Two-tile pair, shared A operand: acc0 = A*B0, acc1 = A*B1.
template<typename FA, typename FB0, typename FB1>
__device__ __forceinline__ void run_pair_sharedA(FA la, FB0 lb0, FB1 lb1,
                                                 fx4 (&acc0)[4][4], fx4 (&acc1)[4][4]){
  bf16x8 a[2][4], b0[2][4], b1[2][4];
  #pragma unroll
  for (int mi=0;mi<4;mi++){ a[0][mi]=la(mi,0); b0[0][mi]=lb0(mi,0); b1[0][mi]=lb1(mi,0); }
  #pragma unroll
  for (int ks=0; ks<4; ks++){
    int cur = ks&1, nxt = cur^1;
    if (ks<3){
      #pragma unroll
      for (int mi=0;mi<4;mi++){ a[nxt][mi]=la(mi,ks+1); b0[nxt][mi]=lb0(mi,ks+1); b1[nxt][mi]=lb1(mi,ks+1); }
    }
    #pragma unroll
    for (int mi=0;mi<4;mi++)
      #pragma unroll
      for (int ni=0;ni<4;ni++){
        acc0[mi][ni] = __builtin_amdgcn_mfma_f32_16x16x32_bf16(a[cur][mi], b0[cur][ni], acc0[mi][ni], 0, 0, 0);
        acc1[mi][ni] = __builtin_amdgcn_mfma_f32_16x16x32_bf16(a[cur][mi], b1[cur][ni], acc1[mi][ni], 0, 0, 0);
      }
  }
}

// ================= K1: prep || castfe || dwconv (independent, blockIdx-partitioned) =====
__global__ __launch_bounds__(256) void k1_prep_cast_conv(
    const float* __restrict__ in_w, const float* __restrict__ ph_w,
    const float* __restrict__ out_w, const float* __restrict__ fe,
    const float* __restrict__ x, const float* __restrict__ dw_w,
    const float* __restrict__ dw_b,
    unsigned short* __restrict__ basis_bf, unsigned short* __restrict__ basisT_bf,
    unsigned short* __restrict__ ph_w_bf, unsigned short* __restrict__ in_w_bf,
    unsigned short* __restrict__ out_w_bf, unsigned short* __restrict__ feb,
    unsigned short* __restrict__ conv)
{
  int blk = blockIdx.x;
  int t = threadIdx.x;
  if (blk < 128){
    // ---- prep ----
    if (t >= 128) return;
    int n = blk, h = t;
    double arg = (double)(n*(2*h+1)) * (M_PI/256.0);
    double v = cos(arg) * 0.125;
    if (n==0) v *= 0.7071067811865476;
    unsigned short bv = f2bf((float)v);
    basis_bf[n*128+h]  = bv;
    basisT_bf[h*128+n] = bv;
    ph_w_bf[n*128+h]  = f2bf(ph_w[n*128+h]);
    in_w_bf[n*128+h]        = f2bf(in_w[n*128+h]);
    in_w_bf[(n+128)*128+h]  = f2bf(in_w[(n+128)*128+h]);
    out_w_bf[n*128+h]       = f2bf(out_w[n*128+h]);
    return;
  }
  if (blk < 1152){
    // ---- castfe ----
    int idx = (blk-128)*256 + t;
    const float* s = fe + (size_t)idx*8;
    float4 f0 = *(const float4*)s;
    float4 f1 = *(const float4*)(s+4);
    unsigned short o[8];
    o[0]=f2bf(f0.x); o[1]=f2bf(f0.y); o[2]=f2bf(f0.z); o[3]=f2bf(f0.w);
    o[4]=f2bf(f1.x); o[5]=f2bf(f1.y); o[6]=f2bf(f1.z); o[7]=f2bf(f1.w);
    *(int4*)(feb + (size_t)idx*8) = *(const int4*)o;
    return;
  }
  // ---- dwconv ----
  {
    int bb = blk - 1152;           // plane*4 + band
    int plane = bb >> 2, band = bb & 3;
    int c = plane & 127;
    const float* xp = x + (size_t)plane*16384;
    unsigned short* op = conv + (size_t)plane*16384;
    const float* kw = dw_w + c*9;
    float k0=kw[0],k1=kw[1],k2=kw[2],k3=kw[3],k4=kw[4],k5=kw[5],k6=kw[6],k7=kw[7],k8=kw[8];
    float bias = dw_b[c];
    int q = t & 31;
    int w0 = q*4;
    int rg = t >> 5;
    int h0 = band*32 + rg*4;
    bool le = (q==0), re = (q==31);
    float4 fA, fB, fC; float lA,rA,lB,rB,lC,rC;
    #define LOADROW(hh, f, l, r) { \
      int hc = (hh)<0 ? 0 : ((hh)>127 ? 127 : (hh)); \
      f = *(const float4*)(xp + hc*128 + w0); \
      float lu = __shfl_up(f.w, 1, 32); \
      float rd = __shfl_down(f.x, 1, 32); \
      l = le ? 0.f : lu; \
      r = re ? 0.f : rd; \
      if ((hh)<0 || (hh)>127){ f = make_float4(0.f,0.f,0.f,0.f); l=0.f; r=0.f; } \
    }
    LOADROW(h0-1, fA,lA,rA);
    LOADROW(h0,   fB,lB,rB);
    #pragma unroll
    for (int i=0;i<4;i++){
      LOADROW(h0+1+i, fC,lC,rC);
      float4 o;
      o.x = bias; o.y = bias; o.z = bias; o.w = bias;
      o.x = fmaf(k0,lA,  fmaf(k1,fA.x, fmaf(k2,fA.y, o.x)));
      o.y = fmaf(k0,fA.x,fmaf(k1,fA.y, fmaf(k2,fA.z, o.y)));
      o.z = fmaf(k0,fA.y,fmaf(k1,fA.z, fmaf(k2,fA.w, o.z)));
      o.w = fmaf(k0,fA.z,fmaf(k1,fA.w, fmaf(k2,rA,   o.w)));
      o.x = fmaf(k3,lB,  fmaf(k4,fB.x, fmaf(k5,fB.y, o.x)));
      o.y = fmaf(k3,fB.x,fmaf(k4,fB.y, fmaf(k5,fB.z, o.y)));
      o.z = fmaf(k3,fB.y,fmaf(k4,fB.z, fmaf(k5,fB.w, o.z)));
      o.w = fmaf(k3,fB.z,fmaf(k4,fB.w, fmaf(k5,rB,   o.w)));
      o.x = fmaf(k6,lC,  fmaf(k7,fC.x, fmaf(k8,fC.y, o.x)));
      o.y = fmaf(k6,fC.x,fmaf(k7,fC.y, fmaf(k8,fC.z, o.y)));
      o.z = fmaf(k6,fC.y,fmaf(k7,fC.z, fmaf(k8,fC.w, o.z)));
      o.w = fmaf(k6,fC.z,fmaf(k7,fC.w, fmaf(k8,rC,   o.w)));
      bf16x4 v;
      v[0]=(__bf16)o.x; v[1]=(__bf16)o.y; v[2]=(__bf16)o.z; v[3]=(__bf16)o.w;
      *(bf16x4*)(op + (size_t)(h0+i)*128 + w0) = v;
      fA=fB; lA=lB; rA=rB;
      fB=fC; lB=lC; rB=rC;
    }
    #undef LOADROW
  }
}

// ================= K2: inproj (blocks 0..1023, UNPAIRED) || projk (blocks 1024..1151) ====
__global__ __launch_bounds__(512) void k2_inproj_projk(
  const unsigned short* __restrict__ conv, const unsigned short* __restrict__ in_w_bf,
  const float* __restrict__ in_b, unsigned short* __restrict__ carrier,
  unsigned short* __restrict__ gate,
  const unsigned short* __restrict__ feb, const unsigned short* __restrict__ ph_w_bf,
  float* __restrict__ projT)
{
  int blk = blockIdx.x;
  int t = threadIdx.x;
  if (blk >= 1024){
    // ---- projk (256 active threads) ----
    if (t >= 256) return;
    int r0 = (blk - 1024) * 128;
    int l = t & 63, wid = t >> 6;
    int wm = wid >> 1, wn = wid & 1;
    int lr = l & 15, lk = (l>>4)*8, ld4 = (l>>4)*4;
    fx4 acc[4][4];
    #pragma unroll
    for (int i=0;i<4;i++) for (int j=0;j<4;j++) acc[i][j] = (fx4){0.f,0.f,0.f,0.f};
    run_gemm(
      [&](int mi,int ks)->bf16x8{ return *(const bf16x8*)(feb + (size_t)(r0 + wm*64+mi*16+lr)*128 + ks*32+lk); },
      [&](int ni,int ks)->bf16x8{ return *(const bf16x8*)(ph_w_bf + (size_t)(wn*64+ni*16+lr)*128 + ks*32+lk); },
      acc);
    #pragma unroll
    for (int mi=0;mi<4;mi++)
      #pragma unroll
      for (int ni=0;ni<4;ni++){
        int c = wn*64 + ni*16 + lr;
        int r = r0 + wm*64 + mi*16 + ld4;
        *(fx4*)(projT + (size_t)c*16384 + r) = acc[mi][ni];
      }
    return;
  }
  // ---- inproj (single pixel, r10-validated form) ----
  __shared__ char A[32768];   // [w][c] swizzled bf16; reused as gate transpose buffer
  int b = blk>>7, h = blk&127;
  const unsigned short* C = conv + (size_t)b*2097152 + h*128;  // + c*16384 + w
  // stage A: transpose conv [c][w] -> LDS [w][c] via 4-channel packs
  {
    int wl = t & 63, grp = t >> 6;   // grp 0..7
    #pragma unroll
    for (int p=0;p<2;p++){
      int w = wl + 64*p;
      #pragma unroll
      for (int q=0;q<4;q++){
        int c0 = (q*8 + grp)*4;
        ushort4 v;
        v.x = C[(size_t)(c0+0)*16384 + w];
        v.y = C[(size_t)(c0+1)*16384 + w];
        v.z = C[(size_t)(c0+2)*16384 + w];
        v.w = C[(size_t)(c0+3)*16384 + w];
        *(ushort4*)(A + swz(w, c0*2)) = v;
      }
    }
  }
  __syncthreads();
  int l = t & 63, wid = t >> 6;
  int wm = wid >> 2, wn = wid & 3;   // 2 x 4 waves, 64x64 quadrants over M=128,N=256
  int lr = l & 15, lk = (l>>4)*8, ld4 = (l>>4)*4;
  fx4 acc[4][4];
  #pragma unroll
  for (int i=0;i<4;i++) for (int j=0;j<4;j++) acc[i][j] = (fx4){0.f,0.f,0.f,0.f};
  run_gemm(
    [&](int mi,int ks)->bf16x8{ return *(const bf16x8*)(A + swz(wm*64+mi*16+lr, (ks*32+lk)*2)); },
    [&](int ni,int ks)->bf16x8{ return *(const bf16x8*)(in_w_bf + (size_t)(wn*64+ni*16+lr)*128 + ks*32+lk); },
    acc);
  __syncthreads();   // done reading A; gate waves will overwrite it
  if (wn < 2){
    // carrier: n in [0,128): store bf16 NCHW, 4 consecutive w per 8B store
    #pragma unroll
    for (int mi=0;mi<4;mi++)
      #pragma unroll
      for (int ni=0;ni<4;ni++){
        int n = wn*64 + ni*16 + lr;
        int w0 = wm*64 + mi*16 + ld4;
        float bias = in_b[n];
        ushort4 v;
        v.x=f2bf(acc[mi][ni][0]+bias); v.y=f2bf(acc[mi][ni][1]+bias);
        v.z=f2bf(acc[mi][ni][2]+bias); v.w=f2bf(acc[mi][ni][3]+bias);
        *(ushort4*)(carrier + (size_t)(b*128+n)*16384 + h*128 + w0) = v;
      }
  } else {
    // gate: n in [128,256): silu, write transposed [w][c] into A
    #pragma unroll
    for (int mi=0;mi<4;mi++)
      #pragma unroll
      for (int ni=0;ni<4;ni++){
        int n = wn*64 + ni*16 + lr;     // 128..255
        int c = n - 128;
        int w0 = wm*64 + mi*16 + ld4;
        float bias = in_b[n];
        #pragma unroll
        for (int r=0;r<4;r++){
          float v = acc[mi][ni][r] + bias;
          float s = v / (1.0f + __expf(-v));
          *(unsigned short*)(A + swz(w0+r, c*2)) = f2bf(s);
        }
      }
  }
  __syncthreads();
  // copy gate LDS [w][c] -> global BHWC bf16, coalesced
  {
    unsigned short* gout = gate + ((size_t)(b*128+h))*16384;   // [w][c]
    int w = t >> 2, cq = (t & 3) * 32;
    #pragma unroll
    for (int i=0;i<4;i++){
      int c0 = cq + i*8;
      int4 v = *(const int4*)(A + swz(w, c0*2));
      *(int4*)(gout + w*128 + c0) = v;
    }
  }
}

// ---------------- modfin: factor -> modT[c][q][p]  (q = fe-col = freq-w, p = fe-row = freq-h)
__global__ __launch_bounds__(256) void modfin_kernel(
  const float* __restrict__ projT, const float* __restrict__ ph_b,
  const float* __restrict__ wave_speed, const float* __restrict__ damping,
  float* __restrict__ modT)
{
  int blk = blockIdx.x;
  int c = blk >> 4, qb = blk & 15;
  int t = threadIdx.x;
  int q = qb*8 + (t>>5);
  int p0 = (t & 31)*4;
  float ws0 = wave_speed[0];
  float dmp = damping[0];
  float inv = 1.0f / fmaxf(fabsf(ws0), 1e-6f);
  float dampf = 1.0f + 0.5f*dmp;
  float bc = ph_b[c];
  const float* src = projT + (size_t)c*16384 + q;
  float o[4];
  #pragma unroll
  for (int i=0;i<4;i++){
    float v = src[(size_t)(p0+i)*128] + bc;
    float g = 0.5f*v*(1.0f + erff(v*0.70710678118f));
    float wp = ws0*g;
    o[i] = __cosf(wp) + __sinf(wp)*inv*dampf;
  }
  *(float4*)(modT + ((size_t)c*128 + q)*128 + p0) = make_float4(o[0],o[1],o[2],o[3]);
}

// ---------------- fused wave kernel: 4 chained MFMA GEMM phases, TWO slices per block ----
__global__ __launch_bounds__(256) void wave_kernel(
  const unsigned short* __restrict__ carrier,
  const unsigned short* __restrict__ basis,    // [f][pos] bf16
  const unsigned short* __restrict__ basisT,   // [pos][f] bf16
  const float* __restrict__ modT,              // [c][w-freq][h-freq] fp32
  unsigned short* __restrict__ fused)
{
  __shared__ char U0[32768];
  __shared__ char U1[32768];
  int blk = blockIdx.x;          // 0..511
  int c = blk & 127;
  const unsigned short* X0 = carrier + (size_t)blk*16384;
  const unsigned short* X1 = carrier + (size_t)(blk+512)*16384;
  unsigned short* F0 = fused + (size_t)blk*16384;
  unsigned short* F1 = fused + (size_t)(blk+512)*16384;
  int t = threadIdx.x;
  int l = t & 63, wid = t >> 6;
  int wm = wid >> 1, wn = wid & 1;
  int lr = l & 15, lk = (l>>4)*8, ld4 = (l>>4)*4;
  fx4 acc0[4][4], acc1[4][4];

  #define ZACC { _Pragma("unroll") for (int i=0;i<4;i++) _Pragma("unroll") for (int j=0;j<4;j++){ acc0[i][j]=(fx4){0.f,0.f,0.f,0.f}; acc1[i][j]=(fx4){0.f,0.f,0.f,0.f}; } }
  #define TSTORE(BUF0, BUF1) { \
    _Pragma("unroll") for (int mi=0;mi<4;mi++) \
      _Pragma("unroll") for (int ni=0;ni<4;ni++){ \
        int rr = wn*64 + ni*16 + lr, cc = wm*64 + mi*16 + ld4; \
        bf16x4 v0, v1; \
        v0[0]=(__bf16)acc0[mi][ni][0]; v0[1]=(__bf16)acc0[mi][ni][1]; \
        v0[2]=(__bf16)acc0[mi][ni][2]; v0[3]=(__bf16)acc0[mi][ni][3]; \
        v1[0]=(__bf16)acc1[mi][ni][0]; v1[1]=(__bf16)acc1[mi][ni][1]; \
        v1[2]=(__bf16)acc1[mi][ni][2]; v1[3]=(__bf16)acc1[mi][ni][3]; \
        *(bf16x4*)(BUF0 + swz(rr, cc*2)) = v0; \
        *(bf16x4*)(BUF1 + swz(rr, cc*2)) = v1; \
      } }

  // G1: D1[h][m] = X @ Bw^T
  ZACC;
  run_pair_sharedB(
    [&](int mi,int ks)->bf16x8{ return *(const bf16x8*)(X0 + (size_t)(wm*64+mi*16+lr)*128 + ks*32+lk); },
    [&](int mi,int ks)->bf16x8{ return *(const bf16x8*)(X1 + (size_t)(wm*64+mi*16+lr)*128 + ks*32+lk); },
    [&](int ni,int ks)->bf16x8{ return *(const bf16x8*)(basis + (size_t)(wn*64+ni*16+lr)*128 + ks*32+lk); },
    acc0, acc1);
  TSTORE(U0, U1);                // U = D1^T : [m][h]
  __syncthreads();               // bar 1

  // G2: D2[n][m] = Bh @ U^T, then modulate
  ZACC;
  run_pair_sharedA(
    [&](int mi,int ks)->bf16x8{ return *(const bf16x8*)(basis + (size_t)(wm*64+mi*16+lr)*128 + ks*32+lk); },
    [&](int ni,int ks)->bf16x8{ return *(const bf16x8*)(U0 + swz(wn*64+ni*16+lr, (ks*32+lk)*2)); },
    [&](int ni,int ks)->bf16x8{ return *(const bf16x8*)(U1 + swz(wn*64+ni*16+lr, (ks*32+lk)*2)); },
    acc0, acc1);
  {
    const float* Mc = modT + (size_t)c*16384;
    #pragma unroll
    for (int mi=0;mi<4;mi++)
      #pragma unroll
      for (int ni=0;ni<4;ni++){
        int n0 = wm*64 + mi*16 + ld4, m = wn*64 + ni*16 + lr;
        fx4 mv = *(const fx4*)(Mc + (size_t)m*128 + n0);
        acc0[mi][ni] *= mv;
        acc1[mi][ni] *= mv;
      }
  }
  __syncthreads();               // bar 2
  TSTORE(U0, U1);                // U = D2^T : [m][n]
  __syncthreads();               // bar 3

  // G3: D3[m][h] = U @ Bh
  ZACC;
  run_pair_sharedB(
    [&](int mi,int ks)->bf16x8{ return *(const bf16x8*)(U0 + swz(wm*64+mi*16+lr, (ks*32+lk)*2)); },
    [&](int mi,int ks)->bf16x8{ return *(const bf16x8*)(U1 + swz(wm*64+mi*16+lr, (ks*32+lk)*2)); },
    [&](int ni,int ks)->bf16x8{ return *(const bf16x8*)(basisT + (size_t)(wn*64+ni*16+lr)*128 + ks*32+lk); },
    acc0, acc1);
  __syncthreads();               // bar 4
  TSTORE(U0, U1);                // U = D3^T : [h][m]
  __syncthreads();               // bar 5

  // G4: D4[w][h] = BwT @ U^T
  ZACC;
  run_pair_sharedA(
    [&](int mi,int ks)->bf16x8{ return *(const bf16x8*)(basisT + (size_t)(wm*64+mi*16+lr)*128 + ks*32+lk); },
    [&](int ni,int ks)->bf16x8{ return *(const bf16x8*)(U0 + swz(wn*64+ni*16+lr, (ks*32+lk)*2)); },
    [&](int ni,int ks)->bf16x8{ return *(const bf16x8*)(U1 + swz(wn*64+ni*16+lr, (ks*32+lk)*2)); },
    acc0, acc1);
  #pragma unroll
  for (int mi=0;mi<4;mi++)
    #pragma unroll
    for (int ni=0;ni<4;ni++){
      int hh = wn*64 + ni*16 + lr, w0 = wm*64 + mi*16 + ld4;
      bf16x4 v0, v1;
      v0[0]=(__bf16)acc0[mi][ni][0]; v0[1]=(__bf16)acc0[mi][ni][1];
      v0[2]=(__bf16)acc0[mi][ni][2]; v0[3]=(__bf16)acc0[mi][ni][3];
      v1[0]=(__bf16)acc1[mi][ni][0]; v1[1]=(__bf16)acc1[mi][ni][1];
      v1[2]=(__bf16)acc1[mi][ni][2]; v1[3]=(__bf16)acc1[mi][ni][3];
      *(bf16x4*)(F0 + hh*128 + w0) = v0;
      *(bf16x4*)(F1 + hh*128 + w0) = v1;
    }
  #undef ZACC
  #undef TSTORE
}

// ---------------- final: LN * silu(gate) @ out_w^T + b -> out NCHW fp32 ----------------
__global__ __launch_bounds__(256) void final_kernel(
  const unsigned short* __restrict__ fused, const unsigned short* __restrict__ gate,
  const unsigned short* __restrict__ out_w_bf, const float* __restrict__ out_b,
  const float* __restrict__ ln_w, const float* __restrict__ ln_b,
  float* __restrict__ out)
{
  __shared__ char Fl[32768];   // F [c][w] swizzled bf16
  __shared__ char Al[32768];   // act [w][c] swizzled bf16
  __shared__ float red[256], red2[256];
  __shared__ float mu[128], rs[128];
  int blk = blockIdx.x; int b = blk>>7, h = blk&127;
  const unsigned short* Fsrc = fused + (size_t)b*2097152 + h*128;  // + c*16384 + w
  const unsigned short* G = gate + (size_t)blk*16384;              // [w][c]
  int t = threadIdx.x;
  // stage F [c][w]
  {
    int c = t>>1, wq = (t&1)*64;
    #pragma unroll
    for (int i=0;i<8;i++){
      int w0 = wq + i*8;
      int4 v = *(const int4*)(Fsrc + (size_t)c*16384 + w0);
      *(int4*)(Fl + swz(c, w0*2)) = v;
    }
  }
  __syncthreads();
  // LN stats per w (reduce over c)
  {
    int w = t&127, half = t>>7;
    float s=0.f, q=0.f;
    for (int i=0;i<64;i++){
      int c = half*64 + i;
      float f = bf2f(*(const unsigned short*)(Fl + swz(c, w*2)));
      s += f; q = fmaf(f,f,q);
    }
    red[t]=s; red2[t]=q;
  }
  __syncthreads();
  if (t < 128){
    float ss = red[t]+red[t+128], qq = red2[t]+red2[t+128];
    float m = ss*(1.f/128.f);
    float var = qq*(1.f/128.f) - m*m;
    mu[t]=m; rs[t]=rsqrtf(var+1e-5f);
  }
  __syncthreads();
  // act[w][c] = LN(F)*silu_gate
  {
    int w = t>>1, cq = (t&1)*64;
    float m_ = mu[w], r_ = rs[w];
    #pragma unroll
    for (int i=0;i<8;i++){
      int c0 = cq + i*8;
      ushort4 g0 = *(const ushort4*)(G + (size_t)w*128 + c0);
      ushort4 g1 = *(const ushort4*)(G + (size_t)w*128 + c0 + 4);
      unsigned short ov[8];
      unsigned short gv[8] = {g0.x,g0.y,g0.z,g0.w,g1.x,g1.y,g1.z,g1.w};
      #pragma unroll
      for (int j=0;j<8;j++){
        int cc = c0+j;
        float f = bf2f(*(const unsigned short*)(Fl + swz(cc, w*2)));
        float a = fmaf((f-m_)*r_, ln_w[cc], ln_b[cc]) * bf2f(gv[j]);
        ov[j] = f2bf(a);
      }
      *(int4*)(Al + swz(w, c0*2)) = *(const int4*)ov;
    }
  }
  __syncthreads();
  // MFMA: D[w][j] = act @ out_w^T
  int l = t & 63, wid = t >> 6;
  int wm = wid >> 1, wn = wid & 1;
  int lr = l & 15, lk = (l>>4)*8, ld4 = (l>>4)*4;
  fx4 acc[4][4];
  #pragma unroll
  for (int i=0;i<4;i++) for (int j=0;j<4;j++) acc[i][j] = (fx4){0.f,0.f,0.f,0.f};
  run_gemm(
    [&](int mi,int ks)->bf16x8{ return *(const bf16x8*)(Al + swz(wm*64+mi*16+lr, (ks*32+lk)*2)); },
    [&](int ni,int ks)->bf16x8{ return *(const bf16x8*)(out_w_bf + (size_t)(wn*64+ni*16+lr)*128 + ks*32+lk); },
    acc);
  #pragma unroll
  for (int mi=0;mi<4;mi++)
    #pragma unroll
    for (int ni=0;ni<4;ni++){
      int j = wn*64 + ni*16 + lr, w0 = wm*64 + mi*16 + ld4;
      float bj = out_b[j];
      fx4 o = acc[mi][ni];
      o[0]+=bj; o[1]+=bj; o[2]+=bj; o[3]+=bj;
      *(fx4*)(out + ((size_t)(b*128 + j)*128 + h)*128 + w0) = o;
    }
}

extern "C" void kernel_launch(void* const* d_in, const int* in_sizes, int n_in,
                              void* d_out, int out_size, void* d_ws, size_t ws_size,
                              hipStream_t stream)
{
  const float* x      = (const float*)d_in[0];
  const float* dw_w   = (const float*)d_in[1];
  const float* dw_b   = (const float*)d_in[2];
  const float* in_w   = (const float*)d_in[3];
  const float* in_b   = (const float*)d_in[4];
  const float* out_w  = (const float*)d_in[5];
  const float* out_b  = (const float*)d_in[6];
  const float* ln_w   = (const float*)d_in[7];
  const float* ln_b   = (const float*)d_in[8];
  const float* ph_w   = (const float*)d_in[9];
  const float* ph_b   = (const float*)d_in[10];
  const float* wsp    = (const float*)d_in[11];
  const float* dmp    = (const float*)d_in[12];
  const float* fe     = (const float*)d_in[13];
  float* outp = (float*)d_out;

  float* modT  = (float*)d_ws;                 // 2,097,152 f32, [c][w-freq][h-freq]
  float* projT = modT + 2097152;               // 2,097,152 f32
  unsigned short* feb      = (unsigned short*)(projT + 2097152);  // 2,097,152 bf16
  unsigned short* conv     = feb     + 2097152;
  unsigned short* carrier  = conv    + 16777216;
  unsigned short* gate     = carrier + 16777216;
  unsigned short* fusedb   = gate    + 16777216;
  unsigned short* basis_bf = fusedb  + 16777216;
  unsigned short* basisT_bf= basis_bf + 16384;
  unsigned short* in_w_bf  = basisT_bf + 16384;
  unsigned short* out_w_bf = in_w_bf + 32768;
  unsigned short* ph_w_bf  = out_w_bf + 16384;

  k1_prep_cast_conv<<<5248,256,0,stream>>>(in_w, ph_w, out_w, fe, x, dw_w, dw_b,
      basis_bf, basisT_bf, ph_w_bf, in_w_bf, out_w_bf, feb, conv);
  k2_inproj_projk<<<1152,512,0,stream>>>(conv, in_w_bf, in_b, carrier, gate,
      feb, ph_w_bf, projT);
  modfin_kernel<<<2048,256,0,stream>>>(projT, ph_b, wsp, dmp, modT);
  wave_kernel<<<512,256,0,stream>>>(carrier, basis_bf, basisT_bf, modT, fusedb);
  final_kernel<<<1024,256,0,stream>>>(fusedb, gate, out_w_bf, out_b, ln_w, ln_b, outp);
}